// Round 12
// baseline (484.489 us; speedup 1.0000x reference)
//
#include <hip/hip_runtime.h>
#include <math.h>

#define BB 32
#define SS 2048
#define EE 6144
#define KS1 8    // K-split gemm1 (K=2048, 256 k per block)
#define KS2 24   // K-split gemm2 (K=6144, 256 k per block)

typedef __bf16 bf16x8 __attribute__((ext_vector_type(8)));
typedef float f32x16 __attribute__((ext_vector_type(16)));
typedef float f32x4 __attribute__((ext_vector_type(4)));

// ---------------- fused LN + attention (head_dim=1) + residual ----------------
// grid (SS/128, BB); block 256 = 4 waves. xout = attn(LN(xin)) + xin.
// If stats != nullptr: block (0,0) zeroes the split-K counters; block (0,b)
// emits mean/var(ddof=1) of xin row b.
__global__ __launch_bounds__(256) void k_attn(const float* __restrict__ xin,
                                              float* __restrict__ xout,
                                              const float* __restrict__ g,
                                              const float* __restrict__ be,
                                              const float* __restrict__ ipw,
                                              const float* __restrict__ ipb,
                                              const float* __restrict__ owp,
                                              const float* __restrict__ obp,
                                              float* __restrict__ stats,
                                              int* __restrict__ cnt) {
  int b = blockIdx.y;
  const float* xrow = xin + b * SS;
  __shared__ float2 uv[SS];           // (u_j, v_j)  16 KB
  __shared__ float red[16];
  __shared__ float smu, srs, sk1, sk2;
  __shared__ float sp[2][3][2][64];   // [s|t][wave-1][m][il]  3 KB
  int tid = threadIdx.x;
  int lane = tid & 63, wid = tid >> 6;

  if (stats && blockIdx.x == 0 && b == 0 && tid < 96) cnt[tid] = 0;

  // phase 1: LN row stats
  float s = 0.f, s2 = 0.f;
  for (int j = tid; j < SS; j += 256) { float v = xrow[j]; s += v; s2 += v * v; }
  for (int off = 32; off; off >>= 1) { s += __shfl_down(s, off); s2 += __shfl_down(s2, off); }
  if (lane == 0) { red[wid] = s; red[4 + wid] = s2; }
  __syncthreads();
  if (tid == 0) {
    float ts = red[0] + red[1] + red[2] + red[3];
    float ts2 = red[4] + red[5] + red[6] + red[7];
    float mu = ts / SS;
    float var = ts2 / SS - mu * mu;
    smu = mu; srs = rsqrtf(var + 1e-5f);
    if (stats && blockIdx.x == 0) {
      stats[b] = mu;
      stats[BB + b] = (ts2 - SS * mu * mu) / (SS - 1);
    }
  }
  __syncthreads();
  float mu = smu, rs = srs;
  float wq = ipw[0], wk = ipw[1], wv = ipw[2];
  float bq = ipb[0], bk = ipb[1], bv = ipb[2];

  // phase 2: stage (u, v) into LDS + track u extremes (k is affine in u)
  float umax = -1e30f, umin = 1e30f;
  for (int j = tid; j < SS; j += 256) {
    float u = (xrow[j] - mu) * rs * g[j] + be[j];
    uv[j] = make_float2(u, fmaf(u, wv, bv));
    umax = fmaxf(umax, u);
    umin = fminf(umin, u);
  }
  for (int off = 32; off; off >>= 1) {
    umax = fmaxf(umax, __shfl_down(umax, off));
    umin = fminf(umin, __shfl_down(umin, off));
  }
  if (lane == 0) { red[8 + wid] = umax; red[12 + wid] = umin; }
  __syncthreads();
  if (tid == 0) {
    float ux = fmaxf(fmaxf(red[8], red[9]), fmaxf(red[10], red[11]));
    float un = fminf(fminf(red[12], red[13]), fminf(red[14], red[15]));
    sk1 = fmaf(ux, wk, bk);
    sk2 = fmaf(un, wk, bk);
  }
  __syncthreads();
  float k1 = sk1, k2 = sk2;

  // phase 3: softmax-weighted sum; arg = L2E*(q*wk)*u_j + L2E*(q*bk - m)
  const float L2E = 1.4426950408889634f;
  int i0 = blockIdx.x << 7;
  float q0 = fmaf(uv[i0 + lane].x, wq, bq);
  float q1 = fmaf(uv[i0 + 64 + lane].x, wq, bq);
  float m0 = fmaxf(q0 * k1, q0 * k2);
  float m1 = fmaxf(q1 * k1, q1 * k2);
  float a0 = L2E * q0 * wk, c0 = L2E * (q0 * bk - m0);
  float a1 = L2E * q1 * wk, c1 = L2E * (q1 * bk - m1);
  float s0 = 0.f, t0 = 0.f, s1 = 0.f, t1 = 0.f;
  int j0 = wid << 9;
#pragma unroll 4
  for (int j = j0; j < j0 + 512; j++) {
    float2 c = uv[j];
    float e0 = __builtin_amdgcn_exp2f(fmaf(a0, c.x, c0));
    float e1 = __builtin_amdgcn_exp2f(fmaf(a1, c.x, c1));
    s0 += e0; t0 = fmaf(e0, c.y, t0);
    s1 += e1; t1 = fmaf(e1, c.y, t1);
  }
  if (wid) {
    sp[0][wid - 1][0][lane] = s0; sp[0][wid - 1][1][lane] = s1;
    sp[1][wid - 1][0][lane] = t0; sp[1][wid - 1][1][lane] = t1;
  }
  __syncthreads();
  if (wid == 0) {
    s0 += sp[0][0][0][lane] + sp[0][1][0][lane] + sp[0][2][0][lane];
    t0 += sp[1][0][0][lane] + sp[1][1][0][lane] + sp[1][2][0][lane];
    s1 += sp[0][0][1][lane] + sp[0][1][1][lane] + sp[0][2][1][lane];
    t1 += sp[1][0][1][lane] + sp[1][1][1][lane] + sp[1][2][1][lane];
    float ow = owp[0], ob = obp[0];
    int i = i0 + lane;
    xout[b * SS + i] = fmaf(t0 / s0, ow, ob) + xrow[i];
    xout[b * SS + i + 64] = fmaf(t1 / s1, ow, ob) + xrow[i + 64];
  }
}

// ---------------- LayerNorm -> bf16 B-fragment layout Ubf[k/8][32][8] ----------------
__global__ __launch_bounds__(256) void k_ln_bf(const float* __restrict__ x,
                                               const float* __restrict__ g,
                                               const float* __restrict__ be,
                                               __bf16* __restrict__ ubf) {
  int b = blockIdx.x;
  const float* row = x + b * SS;
  float s = 0.f, s2 = 0.f;
  for (int j = threadIdx.x; j < SS; j += 256) { float v = row[j]; s += v; s2 += v * v; }
  __shared__ float sm[8];
  __shared__ float smu, srs;
  for (int off = 32; off; off >>= 1) { s += __shfl_down(s, off); s2 += __shfl_down(s2, off); }
  int lane = threadIdx.x & 63, wid = threadIdx.x >> 6;
  if (lane == 0) { sm[wid] = s; sm[4 + wid] = s2; }
  __syncthreads();
  if (threadIdx.x == 0) {
    float ts = sm[0] + sm[1] + sm[2] + sm[3];
    float ts2 = sm[4] + sm[5] + sm[6] + sm[7];
    float mu = ts / SS;
    float var = ts2 / SS - mu * mu;
    smu = mu;
    srs = rsqrtf(var + 1e-5f);
  }
  __syncthreads();
  float mu = smu, rs = srs;
  int t = threadIdx.x;
  float4 v0 = *reinterpret_cast<const float4*>(row + t * 8);
  float4 v1 = *reinterpret_cast<const float4*>(row + t * 8 + 4);
  float4 g0 = *reinterpret_cast<const float4*>(g + t * 8);
  float4 g1 = *reinterpret_cast<const float4*>(g + t * 8 + 4);
  float4 b0 = *reinterpret_cast<const float4*>(be + t * 8);
  float4 b1 = *reinterpret_cast<const float4*>(be + t * 8 + 4);
  bf16x8 o;
  o[0] = (__bf16)((v0.x - mu) * rs * g0.x + b0.x);
  o[1] = (__bf16)((v0.y - mu) * rs * g0.y + b0.y);
  o[2] = (__bf16)((v0.z - mu) * rs * g0.z + b0.z);
  o[3] = (__bf16)((v0.w - mu) * rs * g0.w + b0.w);
  o[4] = (__bf16)((v1.x - mu) * rs * g1.x + b1.x);
  o[5] = (__bf16)((v1.y - mu) * rs * g1.y + b1.y);
  o[6] = (__bf16)((v1.z - mu) * rs * g1.z + b1.z);
  o[7] = (__bf16)((v1.w - mu) * rs * g1.w + b1.w);
  *reinterpret_cast<bf16x8*>(ubf + t * 256 + b * 8) = o;
}

// ---------------- streaming MFMA GEMM + in-block k-pair reduce + tail-block split-K reduce ----
// grid: (N/64, K/256); block 256 = 4 waves.
// Main: wave w: rgrp=w&1 (rows e0+32*rgrp..+31), khalf=w>>1; khalf=1 dumps acc
// to LDS, khalf=0 adds and stores the block's part slab.
// Tail: per column bx, the LAST block (atomic counter) reduces all gridDim.y
// slabs of its 64 outputs x 32 b and applies the epilogue:
//   hq_out != nullptr : bias + LeakyReLU -> bf16 B-frag layout (gemm1)
//   x_out  != nullptr : bias + residual accumulate into x_out[b][s] (gemm2)
__global__ __launch_bounds__(256, 2) void k_gemm_mfma(const __bf16* __restrict__ Ubf,
                                                      const float* __restrict__ W,
                                                      float* __restrict__ part,
                                                      int K, int N,
                                                      int* __restrict__ cnt,
                                                      const float* __restrict__ bias,
                                                      __bf16* __restrict__ hq_out,
                                                      float* __restrict__ x_out) {
  __shared__ float lsb[32 * 65];   // 8320 B; [0..2047] doubles as k-pair buffer
  __shared__ int slast;
  int tid = threadIdx.x;
  int w = tid >> 6, lane = tid & 63;
  int l31 = lane & 31, h = lane >> 5;
  int rgrp = w & 1, kh = w >> 1;
  int e0 = (blockIdx.x << 6) + (rgrp << 5);
  int kc = (blockIdx.y << 8) + (kh << 7);
  const float* wp = W + (size_t)(e0 + l31) * K + kc + (h << 3);
  const __bf16* up = Ubf + (size_t)((kc >> 3) + h) * 256 + (l31 << 3);

  f32x4 wb[16];
  bf16x8 ub[8];
#pragma unroll
  for (int t = 0; t < 8; ++t) {
    wb[2 * t]     = *reinterpret_cast<const f32x4*>(wp + (t << 4));
    wb[2 * t + 1] = *reinterpret_cast<const f32x4*>(wp + (t << 4) + 4);
    ub[t]         = *reinterpret_cast<const bf16x8*>(up + (t << 9));
  }

  f32x16 acc = {0.f, 0.f, 0.f, 0.f, 0.f, 0.f, 0.f, 0.f,
                0.f, 0.f, 0.f, 0.f, 0.f, 0.f, 0.f, 0.f};
#pragma unroll
  for (int t = 0; t < 8; ++t) {
    bf16x8 av;
    av[0] = (__bf16)wb[2 * t][0];     av[1] = (__bf16)wb[2 * t][1];
    av[2] = (__bf16)wb[2 * t][2];     av[3] = (__bf16)wb[2 * t][3];
    av[4] = (__bf16)wb[2 * t + 1][0]; av[5] = (__bf16)wb[2 * t + 1][1];
    av[6] = (__bf16)wb[2 * t + 1][2]; av[7] = (__bf16)wb[2 * t + 1][3];
    acc = __builtin_amdgcn_mfma_f32_32x32x16_bf16(av, ub[t], acc, 0, 0, 0);
  }

  if (kh == 1) {
#pragma unroll
    for (int r = 0; r < 16; ++r) lsb[rgrp * 1024 + r * 64 + lane] = acc[r];
  }
  __syncthreads();
  if (kh == 0) {
    float* out = part + (size_t)blockIdx.y * ((size_t)N * 32);
#pragma unroll
    for (int r = 0; r < 16; ++r) {
      int e = e0 + (r & 3) + ((r >> 2) << 3) + (h << 2);
      out[(size_t)e * 32 + l31] = acc[r] + lsb[rgrp * 1024 + r * 64 + lane];
    }
  }

  // ---- split-K completion: last block of this column reduces all slabs ----
  __threadfence();                 // release: slab visible device-wide
  __syncthreads();
  if (tid == 0) slast = atomicAdd(&cnt[blockIdx.x], 1);
  __syncthreads();
  if (slast != (int)gridDim.y - 1) return;
  if (tid == 0) cnt[blockIdx.x] = 0;   // self-reset for next dispatch/call
  __threadfence();                 // acquire: invalidate stale caches
  __syncthreads();                 // reuse lsb safely

  int nslab = gridDim.y;
  int col0 = blockIdx.x << 6;      // 64 outputs (e or s), x 32 b = 2048 elems
  const float* pc = part + (size_t)col0 * 32;
  size_t slabsz = (size_t)N * 32;
  float4 ac0 = make_float4(0.f, 0.f, 0.f, 0.f);
  float4 ac1 = make_float4(0.f, 0.f, 0.f, 0.f);
  for (int s = 0; s < nslab; s += 8) {
    float4 v0[8], v1[8];
#pragma unroll
    for (int j = 0; j < 8; j++) {
      const float* sp2 = pc + (size_t)(s + j) * slabsz;
      v0[j] = *reinterpret_cast<const float4*>(sp2 + (tid << 2));
      v1[j] = *reinterpret_cast<const float4*>(sp2 + 1024 + (tid << 2));
    }
#pragma unroll
    for (int j = 0; j < 8; j++) {
      ac0.x += v0[j].x; ac0.y += v0[j].y; ac0.z += v0[j].z; ac0.w += v0[j].w;
      ac1.x += v1[j].x; ac1.y += v1[j].y; ac1.z += v1[j].z; ac1.w += v1[j].w;
    }
  }

  if (hq_out) {
    // gemm1 epilogue: bias + LeakyReLU(0.5) -> stage fp32 in lsb[idx]
    int idx0 = tid << 2;           // elements idx0..idx0+3 ; e = col0+(idx>>5), b = idx&31
    int idx1 = 1024 + (tid << 2);
    float bi0 = bias[col0 + (idx0 >> 5)];
    float bi1 = bias[col0 + (idx1 >> 5)];
    float r0[4] = {ac0.x + bi0, ac0.y + bi0, ac0.z + bi0, ac0.w + bi0};
    float r1[4] = {ac1.x + bi1, ac1.y + bi1, ac1.z + bi1, ac1.w + bi1};
#pragma unroll
    for (int k = 0; k < 4; k++) {
      r0[k] = r0[k] >= 0.f ? r0[k] : 0.5f * r0[k];
      r1[k] = r1[k] >= 0.f ? r1[k] : 0.5f * r1[k];
      lsb[idx0 + k] = r0[k];
      lsb[idx1 + k] = r1[k];
    }
    __syncthreads();
    // pack: thread t -> e-group eg = t>>5, b = t&31; 8 consecutive bf16
    int eg = tid >> 5, b = tid & 31;
    bf16x8 o;
#pragma unroll
    for (int j = 0; j < 8; j++) o[j] = (__bf16)lsb[(eg * 8 + j) * 32 + b];
    *reinterpret_cast<bf16x8*>(hq_out + (size_t)((col0 >> 3) + eg) * 256 + b * 8) = o;
  } else {
    // gemm2 epilogue: transpose-stage, then bias + residual into x_out[b][s]
    int idx0 = tid << 2;
    int idx1 = 1024 + (tid << 2);
    int sq0 = idx0 >> 5, b0 = idx0 & 31;
    int sq1 = idx1 >> 5;
    lsb[(b0 + 0) * 65 + sq0] = ac0.x;
    lsb[(b0 + 1) * 65 + sq0] = ac0.y;
    lsb[(b0 + 2) * 65 + sq0] = ac0.z;
    lsb[(b0 + 3) * 65 + sq0] = ac0.w;
    lsb[(b0 + 0) * 65 + sq1] = ac1.x;
    lsb[(b0 + 1) * 65 + sq1] = ac1.y;
    lsb[(b0 + 2) * 65 + sq1] = ac1.z;
    lsb[(b0 + 3) * 65 + sq1] = ac1.w;
    __syncthreads();
    int r = tid >> 3, sc = (tid & 7) * 8;
    float* xp = x_out + (size_t)r * SS + col0 + sc;
    const float* bp = bias + col0 + sc;
#pragma unroll
    for (int q = 0; q < 8; q++) xp[q] += lsb[r * 65 + sc + q] + bp[q];
  }
}

// ---------------- final renorm to original mean/var ----------------
__global__ __launch_bounds__(256) void k_final(const float* __restrict__ xbuf,
                                               const float* __restrict__ stats,
                                               float* __restrict__ out) {
  int b = blockIdx.x;
  const float* row = xbuf + b * SS;
  float s = 0.f, s2 = 0.f;
  for (int j = threadIdx.x; j < SS; j += 256) { float v = row[j]; s += v; s2 += v * v; }
  __shared__ float sm[8];
  __shared__ float smu, srs;
  for (int off = 32; off; off >>= 1) { s += __shfl_down(s, off); s2 += __shfl_down(s2, off); }
  int lane = threadIdx.x & 63, wid = threadIdx.x >> 6;
  if (lane == 0) { sm[wid] = s; sm[4 + wid] = s2; }
  __syncthreads();
  if (threadIdx.x == 0) {
    float ts = sm[0] + sm[1] + sm[2] + sm[3];
    float ts2 = sm[4] + sm[5] + sm[6] + sm[7];
    float mu = ts / SS;
    float var = (ts2 - SS * mu * mu) / (SS - 1);
    smu = mu;
    srs = rsqrtf(var + 2.220446049250313e-16f);
  }
  __syncthreads();
  float mu = smu, rs = srs;
  float scale = sqrtf(stats[BB + b] + 2.220446049250313e-16f);
  float mean0 = stats[b];
  for (int j = threadIdx.x; j < SS; j += 256) {
    out[b * SS + j] = (row[j] - mu) * rs * scale + mean0;
  }
}

extern "C" void kernel_launch(void* const* d_in, const int* in_sizes, int n_in,
                              void* d_out, int out_size, void* d_ws, size_t ws_size,
                              hipStream_t stream) {
  const float* x         = (const float*)d_in[0];
  const float* attn_ln_g = (const float*)d_in[1];
  const float* attn_ln_b = (const float*)d_in[2];
  const float* ipw       = (const float*)d_in[3];
  const float* ipb       = (const float*)d_in[4];
  const float* out_w     = (const float*)d_in[5];
  const float* out_b     = (const float*)d_in[6];
  const float* mlp_ln_g  = (const float*)d_in[7];
  const float* mlp_ln_b  = (const float*)d_in[8];
  const float* W1        = (const float*)d_in[9];
  const float* b1        = (const float*)d_in[10];
  const float* W2        = (const float*)d_in[11];
  const float* b2        = (const float*)d_in[12];

  float* ws    = (float*)d_ws;
  float* xA    = ws;                              // 65536 f (layer-1 output)
  float* xB    = xA + BB * SS;                    // 65536 f (layer-0 output)
  __bf16* ubf  = (__bf16*)(xB + BB * SS);         // 65536 bf16 (32768 f)
  __bf16* hbf  = (__bf16*)(xB + BB * SS + 32768); // 196608 bf16 (98304 f)
  float* part  = xB + BB * SS + 32768 + 98304;    // 1572864 f (6.3 MB)
  float* stats = part + (size_t)KS1 * EE * 32;    // 64 f
  int*   cnt   = (int*)(stats + 64);              // 96 ints (split-K counters)

  for (int l = 0; l < 2; l++) {
    const float* xin = (l == 0) ? x : xB;
    float* xout      = (l == 0) ? xB : xA;
    // ---- attention block (LN fused; layer 0 also emits stats + zeroes cnt) ----
    k_attn<<<dim3(SS / 128, BB), 256, 0, stream>>>(xin, xout,
                                                   attn_ln_g + l * SS, attn_ln_b + l * SS,
                                                   ipw + l * 3, ipb + l * 3,
                                                   out_w + l, out_b + l,
                                                   l == 0 ? stats : nullptr, cnt);
    // ---- MLP block (split-K GEMMs with fused tail-block reduce) ----
    k_ln_bf<<<BB, 256, 0, stream>>>(xout, mlp_ln_g + l * SS, mlp_ln_b + l * SS, ubf);
    k_gemm_mfma<<<dim3(EE / 64, KS1), 256, 0, stream>>>(ubf, W1 + (size_t)l * EE * SS,
                                                        part, SS, EE, cnt,
                                                        b1 + (size_t)l * EE, hbf, nullptr);
    k_gemm_mfma<<<dim3(SS / 64, KS2), 256, 0, stream>>>(hbf, W2 + (size_t)l * SS * EE,
                                                        part, EE, SS, cnt,
                                                        b2 + (size_t)l * SS, nullptr, xout);
  }

  k_final<<<BB, 256, 0, stream>>>(xA, stats, (float*)d_out);
}

// Round 13
// 134.218 us; speedup vs baseline: 3.6097x; 3.6097x over previous
//
#include <hip/hip_runtime.h>
#include <math.h>

#define BB 32
#define SS 2048
#define EE 6144
#define KS1 4    // K-split gemm1 (K=2048, 512 k per block)
#define KS2 12   // K-split gemm2 (K=6144, 512 k per block)

typedef __bf16 bf16x8 __attribute__((ext_vector_type(8)));
typedef float f32x16 __attribute__((ext_vector_type(16)));
typedef float f32x4 __attribute__((ext_vector_type(4)));

// ---------------- fused LN + attention (head_dim=1) + residual ----------------
// grid (SS/128, BB); block 256 = 4 waves. xout = attn(LN(xin)) + xin.
// If stats != nullptr, block x==0 also emits mean/var(ddof=1) of xin rows.
__global__ __launch_bounds__(256) void k_attn(const float* __restrict__ xin,
                                              float* __restrict__ xout,
                                              const float* __restrict__ g,
                                              const float* __restrict__ be,
                                              const float* __restrict__ ipw,
                                              const float* __restrict__ ipb,
                                              const float* __restrict__ owp,
                                              const float* __restrict__ obp,
                                              float* __restrict__ stats) {
  int b = blockIdx.y;
  const float* xrow = xin + b * SS;
  __shared__ float2 uv[SS];           // (u_j, v_j)  16 KB
  __shared__ float red[16];
  __shared__ float smu, srs, sk1, sk2;
  __shared__ float sp[2][3][2][64];   // [s|t][wave-1][m][il]  3 KB
  int tid = threadIdx.x;
  int lane = tid & 63, wid = tid >> 6;

  // phase 1: LN row stats
  float s = 0.f, s2 = 0.f;
  for (int j = tid; j < SS; j += 256) { float v = xrow[j]; s += v; s2 += v * v; }
  for (int off = 32; off; off >>= 1) { s += __shfl_down(s, off); s2 += __shfl_down(s2, off); }
  if (lane == 0) { red[wid] = s; red[4 + wid] = s2; }
  __syncthreads();
  if (tid == 0) {
    float ts = red[0] + red[1] + red[2] + red[3];
    float ts2 = red[4] + red[5] + red[6] + red[7];
    float mu = ts / SS;
    float var = ts2 / SS - mu * mu;
    smu = mu; srs = rsqrtf(var + 1e-5f);
    if (stats && blockIdx.x == 0) {
      stats[b] = mu;
      stats[BB + b] = (ts2 - SS * mu * mu) / (SS - 1);
    }
  }
  __syncthreads();
  float mu = smu, rs = srs;
  float wq = ipw[0], wk = ipw[1], wv = ipw[2];
  float bq = ipb[0], bk = ipb[1], bv = ipb[2];

  // phase 2: stage (u, v) into LDS + track u extremes (k is affine in u)
  float umax = -1e30f, umin = 1e30f;
  for (int j = tid; j < SS; j += 256) {
    float u = (xrow[j] - mu) * rs * g[j] + be[j];
    uv[j] = make_float2(u, fmaf(u, wv, bv));
    umax = fmaxf(umax, u);
    umin = fminf(umin, u);
  }
  for (int off = 32; off; off >>= 1) {
    umax = fmaxf(umax, __shfl_down(umax, off));
    umin = fminf(umin, __shfl_down(umin, off));
  }
  if (lane == 0) { red[8 + wid] = umax; red[12 + wid] = umin; }
  __syncthreads();
  if (tid == 0) {
    float ux = fmaxf(fmaxf(red[8], red[9]), fmaxf(red[10], red[11]));
    float un = fminf(fminf(red[12], red[13]), fminf(red[14], red[15]));
    sk1 = fmaf(ux, wk, bk);
    sk2 = fmaf(un, wk, bk);
  }
  __syncthreads();
  float k1 = sk1, k2 = sk2;

  // phase 3: softmax-weighted sum; arg = L2E*(q*wk)*u_j + L2E*(q*bk - m)
  const float L2E = 1.4426950408889634f;
  int i0 = blockIdx.x << 7;
  float q0 = fmaf(uv[i0 + lane].x, wq, bq);
  float q1 = fmaf(uv[i0 + 64 + lane].x, wq, bq);
  float m0 = fmaxf(q0 * k1, q0 * k2);
  float m1 = fmaxf(q1 * k1, q1 * k2);
  float a0 = L2E * q0 * wk, c0 = L2E * (q0 * bk - m0);
  float a1 = L2E * q1 * wk, c1 = L2E * (q1 * bk - m1);
  float s0 = 0.f, t0 = 0.f, s1 = 0.f, t1 = 0.f;
  int j0 = wid << 9;
#pragma unroll 4
  for (int j = j0; j < j0 + 512; j++) {
    float2 c = uv[j];
    float e0 = __builtin_amdgcn_exp2f(fmaf(a0, c.x, c0));
    float e1 = __builtin_amdgcn_exp2f(fmaf(a1, c.x, c1));
    s0 += e0; t0 = fmaf(e0, c.y, t0);
    s1 += e1; t1 = fmaf(e1, c.y, t1);
  }
  if (wid) {
    sp[0][wid - 1][0][lane] = s0; sp[0][wid - 1][1][lane] = s1;
    sp[1][wid - 1][0][lane] = t0; sp[1][wid - 1][1][lane] = t1;
  }
  __syncthreads();
  if (wid == 0) {
    s0 += sp[0][0][0][lane] + sp[0][1][0][lane] + sp[0][2][0][lane];
    t0 += sp[1][0][0][lane] + sp[1][1][0][lane] + sp[1][2][0][lane];
    s1 += sp[0][0][1][lane] + sp[0][1][1][lane] + sp[0][2][1][lane];
    t1 += sp[1][0][1][lane] + sp[1][1][1][lane] + sp[1][2][1][lane];
    float ow = owp[0], ob = obp[0];
    int i = i0 + lane;
    xout[b * SS + i] = fmaf(t0 / s0, ow, ob) + xrow[i];
    xout[b * SS + i + 64] = fmaf(t1 / s1, ow, ob) + xrow[i + 64];
  }
}

// ---------------- LayerNorm -> bf16 B-fragment layout Ubf[k/8][32][8] ----------------
__global__ __launch_bounds__(256) void k_ln_bf(const float* __restrict__ x,
                                               const float* __restrict__ g,
                                               const float* __restrict__ be,
                                               __bf16* __restrict__ ubf) {
  int b = blockIdx.x;
  const float* row = x + b * SS;
  float s = 0.f, s2 = 0.f;
  for (int j = threadIdx.x; j < SS; j += 256) { float v = row[j]; s += v; s2 += v * v; }
  __shared__ float sm[8];
  __shared__ float smu, srs;
  for (int off = 32; off; off >>= 1) { s += __shfl_down(s, off); s2 += __shfl_down(s2, off); }
  int lane = threadIdx.x & 63, wid = threadIdx.x >> 6;
  if (lane == 0) { sm[wid] = s; sm[4 + wid] = s2; }
  __syncthreads();
  if (threadIdx.x == 0) {
    float ts = sm[0] + sm[1] + sm[2] + sm[3];
    float ts2 = sm[4] + sm[5] + sm[6] + sm[7];
    float mu = ts / SS;
    float var = ts2 / SS - mu * mu;
    smu = mu;
    srs = rsqrtf(var + 1e-5f);
  }
  __syncthreads();
  float mu = smu, rs = srs;
  int t = threadIdx.x;
  float4 v0 = *reinterpret_cast<const float4*>(row + t * 8);
  float4 v1 = *reinterpret_cast<const float4*>(row + t * 8 + 4);
  float4 g0 = *reinterpret_cast<const float4*>(g + t * 8);
  float4 g1 = *reinterpret_cast<const float4*>(g + t * 8 + 4);
  float4 b0 = *reinterpret_cast<const float4*>(be + t * 8);
  float4 b1 = *reinterpret_cast<const float4*>(be + t * 8 + 4);
  bf16x8 o;
  o[0] = (__bf16)((v0.x - mu) * rs * g0.x + b0.x);
  o[1] = (__bf16)((v0.y - mu) * rs * g0.y + b0.y);
  o[2] = (__bf16)((v0.z - mu) * rs * g0.z + b0.z);
  o[3] = (__bf16)((v0.w - mu) * rs * g0.w + b0.w);
  o[4] = (__bf16)((v1.x - mu) * rs * g1.x + b1.x);
  o[5] = (__bf16)((v1.y - mu) * rs * g1.y + b1.y);
  o[6] = (__bf16)((v1.z - mu) * rs * g1.z + b1.z);
  o[7] = (__bf16)((v1.w - mu) * rs * g1.w + b1.w);
  *reinterpret_cast<bf16x8*>(ubf + t * 256 + b * 8) = o;
}

// ---------------- streaming MFMA GEMM with 4-way in-block k reduce ----------------
// grid: (N/32, K/512); block 256 = 4 waves, all on the same 32 e-rows.
// Wave w covers k-chunk kc + 128*w (24 upfront loads, 8 MFMA).
// Waves 1-3 dump acc to LDS; wave 0 adds all and stores one slab per block.
__global__ __launch_bounds__(256, 2) void k_gemm_mfma(const __bf16* __restrict__ Ubf,
                                                      const float* __restrict__ W,
                                                      float* __restrict__ part,
                                                      int K, int N) {
  __shared__ float ls[3][16][64];  // 12 KB, lane-contiguous: conflict-free
  int tid = threadIdx.x;
  int w = tid >> 6, lane = tid & 63;
  int l31 = lane & 31, h = lane >> 5;
  int e0 = blockIdx.x << 5;
  int kc = (blockIdx.y << 9) + (w << 7);
  const float* wp = W + (size_t)(e0 + l31) * K + kc + (h << 3);
  const __bf16* up = Ubf + (size_t)((kc >> 3) + h) * 256 + (l31 << 3);

  f32x4 wb[16];
  bf16x8 ub[8];
#pragma unroll
  for (int t = 0; t < 8; ++t) {
    wb[2 * t]     = *reinterpret_cast<const f32x4*>(wp + (t << 4));
    wb[2 * t + 1] = *reinterpret_cast<const f32x4*>(wp + (t << 4) + 4);
    ub[t]         = *reinterpret_cast<const bf16x8*>(up + (t << 9));
  }

  f32x16 acc = {0.f, 0.f, 0.f, 0.f, 0.f, 0.f, 0.f, 0.f,
                0.f, 0.f, 0.f, 0.f, 0.f, 0.f, 0.f, 0.f};
#pragma unroll
  for (int t = 0; t < 8; ++t) {
    bf16x8 av;
    av[0] = (__bf16)wb[2 * t][0];     av[1] = (__bf16)wb[2 * t][1];
    av[2] = (__bf16)wb[2 * t][2];     av[3] = (__bf16)wb[2 * t][3];
    av[4] = (__bf16)wb[2 * t + 1][0]; av[5] = (__bf16)wb[2 * t + 1][1];
    av[6] = (__bf16)wb[2 * t + 1][2]; av[7] = (__bf16)wb[2 * t + 1][3];
    acc = __builtin_amdgcn_mfma_f32_32x32x16_bf16(av, ub[t], acc, 0, 0, 0);
  }

  if (w) {
#pragma unroll
    for (int r = 0; r < 16; ++r) ls[w - 1][r][lane] = acc[r];
  }
  __syncthreads();
  if (w == 0) {
    float* out = part + (size_t)blockIdx.y * ((size_t)N * 32);
#pragma unroll
    for (int r = 0; r < 16; ++r) {
      float v = acc[r] + ls[0][r][lane] + ls[1][r][lane] + ls[2][r][lane];
      int e = e0 + (r & 3) + ((r >> 2) << 3) + (h << 2);
      out[(size_t)e * 32 + l31] = v;
    }
  }
}

// ---------------- reduce gemm1 partials (KS1=4): bias + leakyrelu -> hbf ----------------
__global__ __launch_bounds__(256) void k_reduce1(const float* __restrict__ part,
                                                 const float* __restrict__ b1,
                                                 __bf16* __restrict__ hbf) {
  __shared__ float ls[256];
  int t = threadIdx.x;
  int base = blockIdx.x << 8;
  float v[4];
#pragma unroll
  for (int j = 0; j < 4; j++) v[j] = part[(size_t)j * (EE * 32) + base + t];
  float s = (v[0] + v[1]) + (v[2] + v[3]);
  int e = (blockIdx.x << 3) + (t >> 5);
  s += b1[e];
  s = s >= 0.f ? s : 0.5f * s;
  ls[((t & 31) << 3) | (t >> 5)] = s;
  __syncthreads();
  hbf[base + t] = (__bf16)ls[t];
}

// ---------------- reduce gemm2 partials (KS2=12): bias + residual -> xbuf ----------------
__global__ __launch_bounds__(256) void k_reduce2(const float* __restrict__ part,
                                                 const float* __restrict__ b2,
                                                 float* __restrict__ xbuf) {
  __shared__ float ls[32][9];
  int t = threadIdx.x;
  int base = blockIdx.x << 8;
  float v[12];
#pragma unroll
  for (int j = 0; j < 12; j++) v[j] = part[(size_t)j * (SS * 32) + base + t];
  float s = 0.f;
#pragma unroll
  for (int j = 0; j < 12; j++) s += v[j];
  ls[t & 31][t >> 5] = s;
  __syncthreads();
  int r = t >> 3, sc = t & 7;
  int scol = (blockIdx.x << 3) + sc;
  xbuf[(size_t)r * SS + scol] += ls[r][sc] + b2[scol];
}

// ---------------- final renorm to original mean/var ----------------
__global__ __launch_bounds__(256) void k_final(const float* __restrict__ xbuf,
                                               const float* __restrict__ stats,
                                               float* __restrict__ out) {
  int b = blockIdx.x;
  const float* row = xbuf + b * SS;
  float s = 0.f, s2 = 0.f;
  for (int j = threadIdx.x; j < SS; j += 256) { float v = row[j]; s += v; s2 += v * v; }
  __shared__ float sm[8];
  __shared__ float smu, srs;
  for (int off = 32; off; off >>= 1) { s += __shfl_down(s, off); s2 += __shfl_down(s2, off); }
  int lane = threadIdx.x & 63, wid = threadIdx.x >> 6;
  if (lane == 0) { sm[wid] = s; sm[4 + wid] = s2; }
  __syncthreads();
  if (threadIdx.x == 0) {
    float ts = sm[0] + sm[1] + sm[2] + sm[3];
    float ts2 = sm[4] + sm[5] + sm[6] + sm[7];
    float mu = ts / SS;
    float var = (ts2 - SS * mu * mu) / (SS - 1);
    smu = mu;
    srs = rsqrtf(var + 2.220446049250313e-16f);
  }
  __syncthreads();
  float mu = smu, rs = srs;
  float scale = sqrtf(stats[BB + b] + 2.220446049250313e-16f);
  float mean0 = stats[b];
  for (int j = threadIdx.x; j < SS; j += 256) {
    out[b * SS + j] = (row[j] - mu) * rs * scale + mean0;
  }
}

extern "C" void kernel_launch(void* const* d_in, const int* in_sizes, int n_in,
                              void* d_out, int out_size, void* d_ws, size_t ws_size,
                              hipStream_t stream) {
  const float* x         = (const float*)d_in[0];
  const float* attn_ln_g = (const float*)d_in[1];
  const float* attn_ln_b = (const float*)d_in[2];
  const float* ipw       = (const float*)d_in[3];
  const float* ipb       = (const float*)d_in[4];
  const float* out_w     = (const float*)d_in[5];
  const float* out_b     = (const float*)d_in[6];
  const float* mlp_ln_g  = (const float*)d_in[7];
  const float* mlp_ln_b  = (const float*)d_in[8];
  const float* W1        = (const float*)d_in[9];
  const float* b1        = (const float*)d_in[10];
  const float* W2        = (const float*)d_in[11];
  const float* b2        = (const float*)d_in[12];

  float* ws    = (float*)d_ws;
  float* xA    = ws;                              // 65536 f (layer-1 output)
  float* xB    = xA + BB * SS;                    // 65536 f (layer-0 output)
  __bf16* ubf  = (__bf16*)(xB + BB * SS);         // 65536 bf16 (32768 f)
  __bf16* hbf  = (__bf16*)(xB + BB * SS + 32768); // 196608 bf16 (98304 f)
  float* part  = xB + BB * SS + 32768 + 98304;    // 786432 f (3.1 MB)
  float* stats = part + (size_t)KS1 * EE * 32;    // 64 f

  for (int l = 0; l < 2; l++) {
    const float* xin = (l == 0) ? x : xB;
    float* xout      = (l == 0) ? xB : xA;
    // ---- attention block (LN fused; layer 0 also emits input stats) ----
    k_attn<<<dim3(SS / 128, BB), 256, 0, stream>>>(xin, xout,
                                                   attn_ln_g + l * SS, attn_ln_b + l * SS,
                                                   ipw + l * 3, ipb + l * 3,
                                                   out_w + l, out_b + l,
                                                   l == 0 ? stats : nullptr);
    // ---- MLP block ----
    k_ln_bf<<<BB, 256, 0, stream>>>(xout, mlp_ln_g + l * SS, mlp_ln_b + l * SS, ubf);
    k_gemm_mfma<<<dim3(EE / 32, KS1), 256, 0, stream>>>(ubf, W1 + (size_t)l * EE * SS,
                                                        part, SS, EE);
    k_reduce1<<<EE / 8, 256, 0, stream>>>(part, b1 + (size_t)l * EE, hbf);
    k_gemm_mfma<<<dim3(SS / 32, KS2), 256, 0, stream>>>(hbf, W2 + (size_t)l * SS * EE,
                                                        part, EE, SS);
    k_reduce2<<<SS / 8, 256, 0, stream>>>(part, b2 + (size_t)l * SS, xout);
  }

  k_final<<<BB, 256, 0, stream>>>(xA, stats, (float*)d_out);
}

// Round 14
// 124.217 us; speedup vs baseline: 3.9003x; 1.0805x over previous
//
#include <hip/hip_runtime.h>
#include <math.h>

#define BB 32
#define SS 2048
#define EE 6144
#define KS2 12   // K-split gemm2 (K=6144, 512 k per block)

typedef __bf16 bf16x8 __attribute__((ext_vector_type(8)));
typedef float f32x16 __attribute__((ext_vector_type(16)));
typedef float f32x4 __attribute__((ext_vector_type(4)));

// ---------------- fused LN + attention (head_dim=1) + residual ----------------
// grid (SS/128, BB); block 256 = 4 waves. xout = attn(LN(xin)) + xin.
// If stats != nullptr, block x==0 also emits mean/var(ddof=1) of xin rows.
__global__ __launch_bounds__(256) void k_attn(const float* __restrict__ xin,
                                              float* __restrict__ xout,
                                              const float* __restrict__ g,
                                              const float* __restrict__ be,
                                              const float* __restrict__ ipw,
                                              const float* __restrict__ ipb,
                                              const float* __restrict__ owp,
                                              const float* __restrict__ obp,
                                              float* __restrict__ stats) {
  int b = blockIdx.y;
  const float* xrow = xin + b * SS;
  __shared__ float2 uv[SS];           // (u_j, v_j)  16 KB
  __shared__ float red[16];
  __shared__ float smu, srs, sk1, sk2;
  __shared__ float sp[2][3][2][64];   // [s|t][wave-1][m][il]  3 KB
  int tid = threadIdx.x;
  int lane = tid & 63, wid = tid >> 6;

  // phase 1: LN row stats
  float s = 0.f, s2 = 0.f;
  for (int j = tid; j < SS; j += 256) { float v = xrow[j]; s += v; s2 += v * v; }
  for (int off = 32; off; off >>= 1) { s += __shfl_down(s, off); s2 += __shfl_down(s2, off); }
  if (lane == 0) { red[wid] = s; red[4 + wid] = s2; }
  __syncthreads();
  if (tid == 0) {
    float ts = red[0] + red[1] + red[2] + red[3];
    float ts2 = red[4] + red[5] + red[6] + red[7];
    float mu = ts / SS;
    float var = ts2 / SS - mu * mu;
    smu = mu; srs = rsqrtf(var + 1e-5f);
    if (stats && blockIdx.x == 0) {
      stats[b] = mu;
      stats[BB + b] = (ts2 - SS * mu * mu) / (SS - 1);
    }
  }
  __syncthreads();
  float mu = smu, rs = srs;
  float wq = ipw[0], wk = ipw[1], wv = ipw[2];
  float bq = ipb[0], bk = ipb[1], bv = ipb[2];

  // phase 2: stage (u, v) into LDS + track u extremes (k is affine in u)
  float umax = -1e30f, umin = 1e30f;
  for (int j = tid; j < SS; j += 256) {
    float u = (xrow[j] - mu) * rs * g[j] + be[j];
    uv[j] = make_float2(u, fmaf(u, wv, bv));
    umax = fmaxf(umax, u);
    umin = fminf(umin, u);
  }
  for (int off = 32; off; off >>= 1) {
    umax = fmaxf(umax, __shfl_down(umax, off));
    umin = fminf(umin, __shfl_down(umin, off));
  }
  if (lane == 0) { red[8 + wid] = umax; red[12 + wid] = umin; }
  __syncthreads();
  if (tid == 0) {
    float ux = fmaxf(fmaxf(red[8], red[9]), fmaxf(red[10], red[11]));
    float un = fminf(fminf(red[12], red[13]), fminf(red[14], red[15]));
    sk1 = fmaf(ux, wk, bk);
    sk2 = fmaf(un, wk, bk);
  }
  __syncthreads();
  float k1 = sk1, k2 = sk2;

  // phase 3: softmax-weighted sum; arg = L2E*(q*wk)*u_j + L2E*(q*bk - m)
  const float L2E = 1.4426950408889634f;
  int i0 = blockIdx.x << 7;
  float q0 = fmaf(uv[i0 + lane].x, wq, bq);
  float q1 = fmaf(uv[i0 + 64 + lane].x, wq, bq);
  float m0 = fmaxf(q0 * k1, q0 * k2);
  float m1 = fmaxf(q1 * k1, q1 * k2);
  float a0 = L2E * q0 * wk, c0 = L2E * (q0 * bk - m0);
  float a1 = L2E * q1 * wk, c1 = L2E * (q1 * bk - m1);
  float s0 = 0.f, t0 = 0.f, s1 = 0.f, t1 = 0.f;
  int j0 = wid << 9;
#pragma unroll 4
  for (int j = j0; j < j0 + 512; j++) {
    float2 c = uv[j];
    float e0 = __builtin_amdgcn_exp2f(fmaf(a0, c.x, c0));
    float e1 = __builtin_amdgcn_exp2f(fmaf(a1, c.x, c1));
    s0 += e0; t0 = fmaf(e0, c.y, t0);
    s1 += e1; t1 = fmaf(e1, c.y, t1);
  }
  if (wid) {
    sp[0][wid - 1][0][lane] = s0; sp[0][wid - 1][1][lane] = s1;
    sp[1][wid - 1][0][lane] = t0; sp[1][wid - 1][1][lane] = t1;
  }
  __syncthreads();
  if (wid == 0) {
    s0 += sp[0][0][0][lane] + sp[0][1][0][lane] + sp[0][2][0][lane];
    t0 += sp[1][0][0][lane] + sp[1][1][0][lane] + sp[1][2][0][lane];
    s1 += sp[0][0][1][lane] + sp[0][1][1][lane] + sp[0][2][1][lane];
    t1 += sp[1][0][1][lane] + sp[1][1][1][lane] + sp[1][2][1][lane];
    float ow = owp[0], ob = obp[0];
    int i = i0 + lane;
    xout[b * SS + i] = fmaf(t0 / s0, ow, ob) + xrow[i];
    xout[b * SS + i + 64] = fmaf(t1 / s1, ow, ob) + xrow[i + 64];
  }
}

// ---------------- LayerNorm -> bf16 B-fragment layout Ubf[k/8][32][8] ----------------
__global__ __launch_bounds__(256) void k_ln_bf(const float* __restrict__ x,
                                               const float* __restrict__ g,
                                               const float* __restrict__ be,
                                               __bf16* __restrict__ ubf) {
  int b = blockIdx.x;
  const float* row = x + b * SS;
  float s = 0.f, s2 = 0.f;
  for (int j = threadIdx.x; j < SS; j += 256) { float v = row[j]; s += v; s2 += v * v; }
  __shared__ float sm[8];
  __shared__ float smu, srs;
  for (int off = 32; off; off >>= 1) { s += __shfl_down(s, off); s2 += __shfl_down(s2, off); }
  int lane = threadIdx.x & 63, wid = threadIdx.x >> 6;
  if (lane == 0) { sm[wid] = s; sm[4 + wid] = s2; }
  __syncthreads();
  if (threadIdx.x == 0) {
    float ts = sm[0] + sm[1] + sm[2] + sm[3];
    float ts2 = sm[4] + sm[5] + sm[6] + sm[7];
    float mu = ts / SS;
    float var = ts2 / SS - mu * mu;
    smu = mu;
    srs = rsqrtf(var + 1e-5f);
  }
  __syncthreads();
  float mu = smu, rs = srs;
  int t = threadIdx.x;
  float4 v0 = *reinterpret_cast<const float4*>(row + t * 8);
  float4 v1 = *reinterpret_cast<const float4*>(row + t * 8 + 4);
  float4 g0 = *reinterpret_cast<const float4*>(g + t * 8);
  float4 g1 = *reinterpret_cast<const float4*>(g + t * 8 + 4);
  float4 b0 = *reinterpret_cast<const float4*>(be + t * 8);
  float4 b1 = *reinterpret_cast<const float4*>(be + t * 8 + 4);
  bf16x8 o;
  o[0] = (__bf16)((v0.x - mu) * rs * g0.x + b0.x);
  o[1] = (__bf16)((v0.y - mu) * rs * g0.y + b0.y);
  o[2] = (__bf16)((v0.z - mu) * rs * g0.z + b0.z);
  o[3] = (__bf16)((v0.w - mu) * rs * g0.w + b0.w);
  o[4] = (__bf16)((v1.x - mu) * rs * g1.x + b1.x);
  o[5] = (__bf16)((v1.y - mu) * rs * g1.y + b1.y);
  o[6] = (__bf16)((v1.z - mu) * rs * g1.z + b1.z);
  o[7] = (__bf16)((v1.w - mu) * rs * g1.w + b1.w);
  *reinterpret_cast<bf16x8*>(ubf + t * 256 + b * 8) = o;
}

// ---------------- gemm1 full-K: h = LeakyReLU(W1 u + b1) -> hbf directly ----------------
// grid: EE/32 = 192 blocks; block 256 = 4 waves, all on the same 32 e-rows.
// Wave w covers k = w*512 + c*128, c=0..3 (acc carries across chunks).
// 4-way LDS reduce -> fp32 staging [32e][33] -> bias+LeakyReLU+pack to B-frag.
__global__ __launch_bounds__(256, 2) void k_gemm1(const __bf16* __restrict__ Ubf,
                                                  const float* __restrict__ W,
                                                  const float* __restrict__ bias,
                                                  __bf16* __restrict__ hbf) {
  __shared__ float ls[3][16][64];  // 12 KB cross-wave reduce
  __shared__ float st[32][33];     // 4.2 KB epilogue staging
  int tid = threadIdx.x;
  int w = tid >> 6, lane = tid & 63;
  int l31 = lane & 31, h = lane >> 5;
  int e0 = blockIdx.x << 5;

  f32x16 acc = {0.f, 0.f, 0.f, 0.f, 0.f, 0.f, 0.f, 0.f,
                0.f, 0.f, 0.f, 0.f, 0.f, 0.f, 0.f, 0.f};
#pragma unroll
  for (int c = 0; c < 4; ++c) {
    int kc = (w << 9) + (c << 7);
    const float* wp = W + (size_t)(e0 + l31) * SS + kc + (h << 3);
    const __bf16* up = Ubf + (size_t)((kc >> 3) + h) * 256 + (l31 << 3);
    f32x4 wb[16];
    bf16x8 ub[8];
#pragma unroll
    for (int t = 0; t < 8; ++t) {
      wb[2 * t]     = *reinterpret_cast<const f32x4*>(wp + (t << 4));
      wb[2 * t + 1] = *reinterpret_cast<const f32x4*>(wp + (t << 4) + 4);
      ub[t]         = *reinterpret_cast<const bf16x8*>(up + (t << 9));
    }
#pragma unroll
    for (int t = 0; t < 8; ++t) {
      bf16x8 av;
      av[0] = (__bf16)wb[2 * t][0];     av[1] = (__bf16)wb[2 * t][1];
      av[2] = (__bf16)wb[2 * t][2];     av[3] = (__bf16)wb[2 * t][3];
      av[4] = (__bf16)wb[2 * t + 1][0]; av[5] = (__bf16)wb[2 * t + 1][1];
      av[6] = (__bf16)wb[2 * t + 1][2]; av[7] = (__bf16)wb[2 * t + 1][3];
      acc = __builtin_amdgcn_mfma_f32_32x32x16_bf16(av, ub[t], acc, 0, 0, 0);
    }
  }

  if (w) {
#pragma unroll
    for (int r = 0; r < 16; ++r) ls[w - 1][r][lane] = acc[r];
  }
  __syncthreads();
  if (w == 0) {
#pragma unroll
    for (int r = 0; r < 16; ++r) {
      float v = acc[r] + ls[0][r][lane] + ls[1][r][lane] + ls[2][r][lane];
      int row = (r & 3) + ((r >> 2) << 3) + (h << 2);
      st[row][l31] = v;
    }
  }
  __syncthreads();
  // pack: thread t<128: e-group eg = t>>5 (8 e each), b = t&31
  if (tid < 128) {
    int eg = tid >> 5, b = tid & 31;
    bf16x8 o;
#pragma unroll
    for (int j = 0; j < 8; j++) {
      float v = st[eg * 8 + j][b] + bias[e0 + eg * 8 + j];
      o[j] = (__bf16)(v >= 0.f ? v : 0.5f * v);
    }
    *reinterpret_cast<bf16x8*>(hbf + (size_t)((e0 >> 3) + eg) * 256 + b * 8) = o;
  }
}

// ---------------- gemm2 split-K with 4-way in-block k reduce ----------------
// grid: (SS/32, KS2); block 256 = 4 waves, all on the same 32 s-rows.
__global__ __launch_bounds__(256, 2) void k_gemm_mfma(const __bf16* __restrict__ Ubf,
                                                      const float* __restrict__ W,
                                                      float* __restrict__ part,
                                                      int K, int N) {
  __shared__ float ls[3][16][64];
  int tid = threadIdx.x;
  int w = tid >> 6, lane = tid & 63;
  int l31 = lane & 31, h = lane >> 5;
  int e0 = blockIdx.x << 5;
  int kc = (blockIdx.y << 9) + (w << 7);
  const float* wp = W + (size_t)(e0 + l31) * K + kc + (h << 3);
  const __bf16* up = Ubf + (size_t)((kc >> 3) + h) * 256 + (l31 << 3);

  f32x4 wb[16];
  bf16x8 ub[8];
#pragma unroll
  for (int t = 0; t < 8; ++t) {
    wb[2 * t]     = *reinterpret_cast<const f32x4*>(wp + (t << 4));
    wb[2 * t + 1] = *reinterpret_cast<const f32x4*>(wp + (t << 4) + 4);
    ub[t]         = *reinterpret_cast<const bf16x8*>(up + (t << 9));
  }

  f32x16 acc = {0.f, 0.f, 0.f, 0.f, 0.f, 0.f, 0.f, 0.f,
                0.f, 0.f, 0.f, 0.f, 0.f, 0.f, 0.f, 0.f};
#pragma unroll
  for (int t = 0; t < 8; ++t) {
    bf16x8 av;
    av[0] = (__bf16)wb[2 * t][0];     av[1] = (__bf16)wb[2 * t][1];
    av[2] = (__bf16)wb[2 * t][2];     av[3] = (__bf16)wb[2 * t][3];
    av[4] = (__bf16)wb[2 * t + 1][0]; av[5] = (__bf16)wb[2 * t + 1][1];
    av[6] = (__bf16)wb[2 * t + 1][2]; av[7] = (__bf16)wb[2 * t + 1][3];
    acc = __builtin_amdgcn_mfma_f32_32x32x16_bf16(av, ub[t], acc, 0, 0, 0);
  }

  if (w) {
#pragma unroll
    for (int r = 0; r < 16; ++r) ls[w - 1][r][lane] = acc[r];
  }
  __syncthreads();
  if (w == 0) {
    float* out = part + (size_t)blockIdx.y * ((size_t)N * 32);
#pragma unroll
    for (int r = 0; r < 16; ++r) {
      float v = acc[r] + ls[0][r][lane] + ls[1][r][lane] + ls[2][r][lane];
      int e = e0 + (r & 3) + ((r >> 2) << 3) + (h << 2);
      out[(size_t)e * 32 + l31] = v;
    }
  }
}

// ---------------- reduce gemm2 partials (KS2=12): bias + residual -> xbuf ----------------
__global__ __launch_bounds__(256) void k_reduce2(const float* __restrict__ part,
                                                 const float* __restrict__ b2,
                                                 float* __restrict__ xbuf) {
  __shared__ float ls[32][9];
  int t = threadIdx.x;
  int base = blockIdx.x << 8;
  float v[12];
#pragma unroll
  for (int j = 0; j < 12; j++) v[j] = part[(size_t)j * (SS * 32) + base + t];
  float s = 0.f;
#pragma unroll
  for (int j = 0; j < 12; j++) s += v[j];
  ls[t & 31][t >> 5] = s;
  __syncthreads();
  int r = t >> 3, sc = t & 7;
  int scol = (blockIdx.x << 3) + sc;
  xbuf[(size_t)r * SS + scol] += ls[r][sc] + b2[scol];
}

// ---------------- final renorm to original mean/var ----------------
__global__ __launch_bounds__(256) void k_final(const float* __restrict__ xbuf,
                                               const float* __restrict__ stats,
                                               float* __restrict__ out) {
  int b = blockIdx.x;
  const float* row = xbuf + b * SS;
  float s = 0.f, s2 = 0.f;
  for (int j = threadIdx.x; j < SS; j += 256) { float v = row[j]; s += v; s2 += v * v; }
  __shared__ float sm[8];
  __shared__ float smu, srs;
  for (int off = 32; off; off >>= 1) { s += __shfl_down(s, off); s2 += __shfl_down(s2, off); }
  int lane = threadIdx.x & 63, wid = threadIdx.x >> 6;
  if (lane == 0) { sm[wid] = s; sm[4 + wid] = s2; }
  __syncthreads();
  if (threadIdx.x == 0) {
    float ts = sm[0] + sm[1] + sm[2] + sm[3];
    float ts2 = sm[4] + sm[5] + sm[6] + sm[7];
    float mu = ts / SS;
    float var = (ts2 - SS * mu * mu) / (SS - 1);
    smu = mu;
    srs = rsqrtf(var + 2.220446049250313e-16f);
  }
  __syncthreads();
  float mu = smu, rs = srs;
  float scale = sqrtf(stats[BB + b] + 2.220446049250313e-16f);
  float mean0 = stats[b];
  for (int j = threadIdx.x; j < SS; j += 256) {
    out[b * SS + j] = (row[j] - mu) * rs * scale + mean0;
  }
}

extern "C" void kernel_launch(void* const* d_in, const int* in_sizes, int n_in,
                              void* d_out, int out_size, void* d_ws, size_t ws_size,
                              hipStream_t stream) {
  const float* x         = (const float*)d_in[0];
  const float* attn_ln_g = (const float*)d_in[1];
  const float* attn_ln_b = (const float*)d_in[2];
  const float* ipw       = (const float*)d_in[3];
  const float* ipb       = (const float*)d_in[4];
  const float* out_w     = (const float*)d_in[5];
  const float* out_b     = (const float*)d_in[6];
  const float* mlp_ln_g  = (const float*)d_in[7];
  const float* mlp_ln_b  = (const float*)d_in[8];
  const float* W1        = (const float*)d_in[9];
  const float* b1        = (const float*)d_in[10];
  const float* W2        = (const float*)d_in[11];
  const float* b2        = (const float*)d_in[12];

  float* ws    = (float*)d_ws;
  float* xA    = ws;                              // 65536 f (layer-1 output)
  float* xB    = xA + BB * SS;                    // 65536 f (layer-0 output)
  __bf16* ubf  = (__bf16*)(xB + BB * SS);         // 65536 bf16 (32768 f)
  __bf16* hbf  = (__bf16*)(xB + BB * SS + 32768); // 196608 bf16 (98304 f)
  float* part  = xB + BB * SS + 32768 + 98304;    // 786432 f (3.1 MB)
  float* stats = part + (size_t)KS2 * SS * 32;    // 64 f

  for (int l = 0; l < 2; l++) {
    const float* xin = (l == 0) ? x : xB;
    float* xout      = (l == 0) ? xB : xA;
    // ---- attention block (LN fused; layer 0 also emits input stats) ----
    k_attn<<<dim3(SS / 128, BB), 256, 0, stream>>>(xin, xout,
                                                   attn_ln_g + l * SS, attn_ln_b + l * SS,
                                                   ipw + l * 3, ipb + l * 3,
                                                   out_w + l, out_b + l,
                                                   l == 0 ? stats : nullptr);
    // ---- MLP block ----
    k_ln_bf<<<BB, 256, 0, stream>>>(xout, mlp_ln_g + l * SS, mlp_ln_b + l * SS, ubf);
    k_gemm1<<<EE / 32, 256, 0, stream>>>(ubf, W1 + (size_t)l * EE * SS,
                                         b1 + (size_t)l * EE, hbf);
    k_gemm_mfma<<<dim3(SS / 32, KS2), 256, 0, stream>>>(hbf, W2 + (size_t)l * SS * EE,
                                                        part, EE, SS);
    k_reduce2<<<SS / 8, 256, 0, stream>>>(part, b2 + (size_t)l * SS, xout);
  }

  k_final<<<BB, 256, 0, stream>>>(xA, stats, (float*)d_out);
}

// Round 15
// 118.758 us; speedup vs baseline: 4.0796x; 1.0460x over previous
//
#include <hip/hip_runtime.h>
#include <math.h>

#define BB 32
#define SS 2048
#define EE 6144
#define KS2 12   // K-split gemm2 (K=6144, 512 k per block)

typedef __bf16 bf16x8 __attribute__((ext_vector_type(8)));
typedef float f32x16 __attribute__((ext_vector_type(16)));
typedef float f32x4 __attribute__((ext_vector_type(4)));

// ---------------- fused [MLP-tail +] LN + attention + residual ----------------
// grid (SS/128, BB); block 256 = 4 waves.
// Input row = xin[b]                      (mlpPart == nullptr)
//           = xin[b] + b2 + sum_ks part   (mlpPart != nullptr, b-major part)
// xout = attn(LN(row)) + row.  If stats != nullptr, block x==0 emits
// mean/var(ddof=1) of the input row.
__global__ __launch_bounds__(256) void k_attn(const float* __restrict__ xin,
                                              float* __restrict__ xout,
                                              const float* __restrict__ g,
                                              const float* __restrict__ be,
                                              const float* __restrict__ ipw,
                                              const float* __restrict__ ipb,
                                              const float* __restrict__ owp,
                                              const float* __restrict__ obp,
                                              float* __restrict__ stats,
                                              const float* __restrict__ mlpPart,
                                              const float* __restrict__ b2) {
  int b = blockIdx.y;
  const float* xrow = xin + b * SS;
  __shared__ float rowbuf[SS];        // 8 KB reconstructed input row
  __shared__ float2 uv[SS];           // (u_j, v_j)  16 KB
  __shared__ float red[16];
  __shared__ float smu, srs, sk1, sk2;
  __shared__ float sp[2][3][2][64];   // 3 KB
  int tid = threadIdx.x;
  int lane = tid & 63, wid = tid >> 6;

  // phase 0: build input row
  float4* rb4 = reinterpret_cast<float4*>(rowbuf);
  const float4* xr4 = reinterpret_cast<const float4*>(xrow);
  if (mlpPart) {
    const float4* b24 = reinterpret_cast<const float4*>(b2);
#pragma unroll
    for (int it = 0; it < 2; ++it) {
      int jj = tid + (it << 8);
      float4 xv = xr4[jj];
      float4 bv = b24[jj];
      float4 pv[KS2];
#pragma unroll
      for (int ks = 0; ks < KS2; ks++)
        pv[ks] = reinterpret_cast<const float4*>(mlpPart + (size_t)ks * (32 * SS) + (size_t)b * SS)[jj];
      float4 o;
      o.x = xv.x + bv.x; o.y = xv.y + bv.y; o.z = xv.z + bv.z; o.w = xv.w + bv.w;
#pragma unroll
      for (int ks = 0; ks < KS2; ks++) {
        o.x += pv[ks].x; o.y += pv[ks].y; o.z += pv[ks].z; o.w += pv[ks].w;
      }
      rb4[jj] = o;
    }
  } else {
#pragma unroll
    for (int it = 0; it < 2; ++it) {
      int jj = tid + (it << 8);
      rb4[jj] = xr4[jj];
    }
  }
  __syncthreads();

  // phase 1: LN row stats (from rowbuf)
  float s = 0.f, s2 = 0.f;
  for (int j = tid; j < SS; j += 256) { float v = rowbuf[j]; s += v; s2 += v * v; }
  for (int off = 32; off; off >>= 1) { s += __shfl_down(s, off); s2 += __shfl_down(s2, off); }
  if (lane == 0) { red[wid] = s; red[4 + wid] = s2; }
  __syncthreads();
  if (tid == 0) {
    float ts = red[0] + red[1] + red[2] + red[3];
    float ts2 = red[4] + red[5] + red[6] + red[7];
    float mu = ts / SS;
    float var = ts2 / SS - mu * mu;
    smu = mu; srs = rsqrtf(var + 1e-5f);
    if (stats && blockIdx.x == 0) {
      stats[b] = mu;
      stats[BB + b] = (ts2 - SS * mu * mu) / (SS - 1);
    }
  }
  __syncthreads();
  float mu = smu, rs = srs;
  float wq = ipw[0], wk = ipw[1], wv = ipw[2];
  float bq = ipb[0], bk = ipb[1], bv = ipb[2];

  // phase 2: stage (u, v) into LDS + track u extremes (k is affine in u)
  float umax = -1e30f, umin = 1e30f;
  for (int j = tid; j < SS; j += 256) {
    float u = (rowbuf[j] - mu) * rs * g[j] + be[j];
    uv[j] = make_float2(u, fmaf(u, wv, bv));
    umax = fmaxf(umax, u);
    umin = fminf(umin, u);
  }
  for (int off = 32; off; off >>= 1) {
    umax = fmaxf(umax, __shfl_down(umax, off));
    umin = fminf(umin, __shfl_down(umin, off));
  }
  if (lane == 0) { red[8 + wid] = umax; red[12 + wid] = umin; }
  __syncthreads();
  if (tid == 0) {
    float ux = fmaxf(fmaxf(red[8], red[9]), fmaxf(red[10], red[11]));
    float un = fminf(fminf(red[12], red[13]), fminf(red[14], red[15]));
    sk1 = fmaf(ux, wk, bk);
    sk2 = fmaf(un, wk, bk);
  }
  __syncthreads();
  float k1 = sk1, k2 = sk2;

  // phase 3: softmax-weighted sum; arg = L2E*(q*wk)*u_j + L2E*(q*bk - m)
  const float L2E = 1.4426950408889634f;
  int i0 = blockIdx.x << 7;
  float q0 = fmaf(uv[i0 + lane].x, wq, bq);
  float q1 = fmaf(uv[i0 + 64 + lane].x, wq, bq);
  float m0 = fmaxf(q0 * k1, q0 * k2);
  float m1 = fmaxf(q1 * k1, q1 * k2);
  float a0 = L2E * q0 * wk, c0 = L2E * (q0 * bk - m0);
  float a1 = L2E * q1 * wk, c1 = L2E * (q1 * bk - m1);
  float s0 = 0.f, t0 = 0.f, s1 = 0.f, t1 = 0.f;
  int j0 = wid << 9;
#pragma unroll 4
  for (int j = j0; j < j0 + 512; j++) {
    float2 c = uv[j];
    float e0 = __builtin_amdgcn_exp2f(fmaf(a0, c.x, c0));
    float e1 = __builtin_amdgcn_exp2f(fmaf(a1, c.x, c1));
    s0 += e0; t0 = fmaf(e0, c.y, t0);
    s1 += e1; t1 = fmaf(e1, c.y, t1);
  }
  if (wid) {
    sp[0][wid - 1][0][lane] = s0; sp[0][wid - 1][1][lane] = s1;
    sp[1][wid - 1][0][lane] = t0; sp[1][wid - 1][1][lane] = t1;
  }
  __syncthreads();
  if (wid == 0) {
    s0 += sp[0][0][0][lane] + sp[0][1][0][lane] + sp[0][2][0][lane];
    t0 += sp[1][0][0][lane] + sp[1][1][0][lane] + sp[1][2][0][lane];
    s1 += sp[0][0][1][lane] + sp[0][1][1][lane] + sp[0][2][1][lane];
    t1 += sp[1][0][1][lane] + sp[1][1][1][lane] + sp[1][2][1][lane];
    float ow = owp[0], ob = obp[0];
    int i = i0 + lane;
    xout[b * SS + i] = fmaf(t0 / s0, ow, ob) + rowbuf[i];
    xout[b * SS + i + 64] = fmaf(t1 / s1, ow, ob) + rowbuf[i + 64];
  }
}

// ---------------- LayerNorm -> bf16 B-fragment layout Ubf[k/8][32][8] ----------------
__global__ __launch_bounds__(256) void k_ln_bf(const float* __restrict__ x,
                                               const float* __restrict__ g,
                                               const float* __restrict__ be,
                                               __bf16* __restrict__ ubf) {
  int b = blockIdx.x;
  const float* row = x + b * SS;
  float s = 0.f, s2 = 0.f;
  for (int j = threadIdx.x; j < SS; j += 256) { float v = row[j]; s += v; s2 += v * v; }
  __shared__ float sm[8];
  __shared__ float smu, srs;
  for (int off = 32; off; off >>= 1) { s += __shfl_down(s, off); s2 += __shfl_down(s2, off); }
  int lane = threadIdx.x & 63, wid = threadIdx.x >> 6;
  if (lane == 0) { sm[wid] = s; sm[4 + wid] = s2; }
  __syncthreads();
  if (threadIdx.x == 0) {
    float ts = sm[0] + sm[1] + sm[2] + sm[3];
    float ts2 = sm[4] + sm[5] + sm[6] + sm[7];
    float mu = ts / SS;
    float var = ts2 / SS - mu * mu;
    smu = mu;
    srs = rsqrtf(var + 1e-5f);
  }
  __syncthreads();
  float mu = smu, rs = srs;
  int t = threadIdx.x;
  float4 v0 = *reinterpret_cast<const float4*>(row + t * 8);
  float4 v1 = *reinterpret_cast<const float4*>(row + t * 8 + 4);
  float4 g0 = *reinterpret_cast<const float4*>(g + t * 8);
  float4 g1 = *reinterpret_cast<const float4*>(g + t * 8 + 4);
  float4 b0 = *reinterpret_cast<const float4*>(be + t * 8);
  float4 b1 = *reinterpret_cast<const float4*>(be + t * 8 + 4);
  bf16x8 o;
  o[0] = (__bf16)((v0.x - mu) * rs * g0.x + b0.x);
  o[1] = (__bf16)((v0.y - mu) * rs * g0.y + b0.y);
  o[2] = (__bf16)((v0.z - mu) * rs * g0.z + b0.z);
  o[3] = (__bf16)((v0.w - mu) * rs * g0.w + b0.w);
  o[4] = (__bf16)((v1.x - mu) * rs * g1.x + b1.x);
  o[5] = (__bf16)((v1.y - mu) * rs * g1.y + b1.y);
  o[6] = (__bf16)((v1.z - mu) * rs * g1.z + b1.z);
  o[7] = (__bf16)((v1.w - mu) * rs * g1.w + b1.w);
  *reinterpret_cast<bf16x8*>(ubf + t * 256 + b * 8) = o;
}

// ---------------- gemm1 full-K: h = LeakyReLU(W1 u + b1) -> hbf directly ----------------
__global__ __launch_bounds__(256, 2) void k_gemm1(const __bf16* __restrict__ Ubf,
                                                  const float* __restrict__ W,
                                                  const float* __restrict__ bias,
                                                  __bf16* __restrict__ hbf) {
  __shared__ float ls[3][16][64];  // 12 KB cross-wave reduce
  __shared__ float st[32][33];     // 4.2 KB epilogue staging
  int tid = threadIdx.x;
  int w = tid >> 6, lane = tid & 63;
  int l31 = lane & 31, h = lane >> 5;
  int e0 = blockIdx.x << 5;

  f32x16 acc = {0.f, 0.f, 0.f, 0.f, 0.f, 0.f, 0.f, 0.f,
                0.f, 0.f, 0.f, 0.f, 0.f, 0.f, 0.f, 0.f};
#pragma unroll
  for (int c = 0; c < 4; ++c) {
    int kc = (w << 9) + (c << 7);
    const float* wp = W + (size_t)(e0 + l31) * SS + kc + (h << 3);
    const __bf16* up = Ubf + (size_t)((kc >> 3) + h) * 256 + (l31 << 3);
    f32x4 wb[16];
    bf16x8 ub[8];
#pragma unroll
    for (int t = 0; t < 8; ++t) {
      wb[2 * t]     = *reinterpret_cast<const f32x4*>(wp + (t << 4));
      wb[2 * t + 1] = *reinterpret_cast<const f32x4*>(wp + (t << 4) + 4);
      ub[t]         = *reinterpret_cast<const bf16x8*>(up + (t << 9));
    }
#pragma unroll
    for (int t = 0; t < 8; ++t) {
      bf16x8 av;
      av[0] = (__bf16)wb[2 * t][0];     av[1] = (__bf16)wb[2 * t][1];
      av[2] = (__bf16)wb[2 * t][2];     av[3] = (__bf16)wb[2 * t][3];
      av[4] = (__bf16)wb[2 * t + 1][0]; av[5] = (__bf16)wb[2 * t + 1][1];
      av[6] = (__bf16)wb[2 * t + 1][2]; av[7] = (__bf16)wb[2 * t + 1][3];
      acc = __builtin_amdgcn_mfma_f32_32x32x16_bf16(av, ub[t], acc, 0, 0, 0);
    }
  }

  if (w) {
#pragma unroll
    for (int r = 0; r < 16; ++r) ls[w - 1][r][lane] = acc[r];
  }
  __syncthreads();
  if (w == 0) {
#pragma unroll
    for (int r = 0; r < 16; ++r) {
      float v = acc[r] + ls[0][r][lane] + ls[1][r][lane] + ls[2][r][lane];
      int row = (r & 3) + ((r >> 2) << 3) + (h << 2);
      st[row][l31] = v;
    }
  }
  __syncthreads();
  if (tid < 128) {
    int eg = tid >> 5, b = tid & 31;
    bf16x8 o;
#pragma unroll
    for (int j = 0; j < 8; j++) {
      float v = st[eg * 8 + j][b] + bias[e0 + eg * 8 + j];
      o[j] = (__bf16)(v >= 0.f ? v : 0.5f * v);
    }
    *reinterpret_cast<bf16x8*>(hbf + (size_t)((e0 >> 3) + eg) * 256 + b * 8) = o;
  }
}

// ---------------- gemm2 split-K, b-major partial store part[ks][b][s] ----------------
// grid: (SS/32, KS2); block 256 = 4 waves, all on the same 32 s-rows.
__global__ __launch_bounds__(256, 2) void k_gemm2(const __bf16* __restrict__ Ubf,
                                                  const float* __restrict__ W,
                                                  float* __restrict__ part,
                                                  int K) {
  __shared__ float ls[3][16][64];  // 12 KB
  __shared__ float st[32][33];     // 4.2 KB transpose staging
  int tid = threadIdx.x;
  int w = tid >> 6, lane = tid & 63;
  int l31 = lane & 31, h = lane >> 5;
  int s0 = blockIdx.x << 5;
  int kc = (blockIdx.y << 9) + (w << 7);
  const float* wp = W + (size_t)(s0 + l31) * K + kc + (h << 3);
  const __bf16* up = Ubf + (size_t)((kc >> 3) + h) * 256 + (l31 << 3);

  f32x4 wb[16];
  bf16x8 ub[8];
#pragma unroll
  for (int t = 0; t < 8; ++t) {
    wb[2 * t]     = *reinterpret_cast<const f32x4*>(wp + (t << 4));
    wb[2 * t + 1] = *reinterpret_cast<const f32x4*>(wp + (t << 4) + 4);
    ub[t]         = *reinterpret_cast<const bf16x8*>(up + (t << 9));
  }

  f32x16 acc = {0.f, 0.f, 0.f, 0.f, 0.f, 0.f, 0.f, 0.f,
                0.f, 0.f, 0.f, 0.f, 0.f, 0.f, 0.f, 0.f};
#pragma unroll
  for (int t = 0; t < 8; ++t) {
    bf16x8 av;
    av[0] = (__bf16)wb[2 * t][0];     av[1] = (__bf16)wb[2 * t][1];
    av[2] = (__bf16)wb[2 * t][2];     av[3] = (__bf16)wb[2 * t][3];
    av[4] = (__bf16)wb[2 * t + 1][0]; av[5] = (__bf16)wb[2 * t + 1][1];
    av[6] = (__bf16)wb[2 * t + 1][2]; av[7] = (__bf16)wb[2 * t + 1][3];
    acc = __builtin_amdgcn_mfma_f32_32x32x16_bf16(av, ub[t], acc, 0, 0, 0);
  }

  if (w) {
#pragma unroll
    for (int r = 0; r < 16; ++r) ls[w - 1][r][lane] = acc[r];
  }
  __syncthreads();
  if (w == 0) {
#pragma unroll
    for (int r = 0; r < 16; ++r) {
      float v = acc[r] + ls[0][r][lane] + ls[1][r][lane] + ls[2][r][lane];
      int row = (r & 3) + ((r >> 2) << 3) + (h << 2);   // s_local
      st[row][l31] = v;                                  // [s_local][b]
    }
  }
  __syncthreads();
  // b-major store: thread t -> b = t>>3, s-quad i0 = (t&7)*4
  {
    float* out = part + (size_t)blockIdx.y * (32 * SS);
    int bb = tid >> 3, i0 = (tid & 7) << 2;
    float4 o4;
    o4.x = st[i0 + 0][bb];
    o4.y = st[i0 + 1][bb];
    o4.z = st[i0 + 2][bb];
    o4.w = st[i0 + 3][bb];
    *reinterpret_cast<float4*>(out + (size_t)bb * SS + s0 + i0) = o4;
  }
}

// ---------------- final: row = xA + b2 + sum part; renorm to original stats ----------------
__global__ __launch_bounds__(256) void k_final(const float* __restrict__ xbuf,
                                               const float* __restrict__ part,
                                               const float* __restrict__ b2,
                                               const float* __restrict__ stats,
                                               float* __restrict__ out) {
  int b = blockIdx.x;
  __shared__ float rowbuf[SS];
  __shared__ float sm[8];
  __shared__ float smu, srs;
  int tid = threadIdx.x;
  float4* rb4 = reinterpret_cast<float4*>(rowbuf);
  const float4* xr4 = reinterpret_cast<const float4*>(xbuf + (size_t)b * SS);
  const float4* b24 = reinterpret_cast<const float4*>(b2);
#pragma unroll
  for (int it = 0; it < 2; ++it) {
    int jj = tid + (it << 8);
    float4 xv = xr4[jj];
    float4 bv = b24[jj];
    float4 pv[KS2];
#pragma unroll
    for (int ks = 0; ks < KS2; ks++)
      pv[ks] = reinterpret_cast<const float4*>(part + (size_t)ks * (32 * SS) + (size_t)b * SS)[jj];
    float4 o;
    o.x = xv.x + bv.x; o.y = xv.y + bv.y; o.z = xv.z + bv.z; o.w = xv.w + bv.w;
#pragma unroll
    for (int ks = 0; ks < KS2; ks++) {
      o.x += pv[ks].x; o.y += pv[ks].y; o.z += pv[ks].z; o.w += pv[ks].w;
    }
    rb4[jj] = o;
  }
  __syncthreads();

  float s = 0.f, s2 = 0.f;
  for (int j = tid; j < SS; j += 256) { float v = rowbuf[j]; s += v; s2 += v * v; }
  for (int off = 32; off; off >>= 1) { s += __shfl_down(s, off); s2 += __shfl_down(s2, off); }
  int lane = tid & 63, wid = tid >> 6;
  if (lane == 0) { sm[wid] = s; sm[4 + wid] = s2; }
  __syncthreads();
  if (tid == 0) {
    float ts = sm[0] + sm[1] + sm[2] + sm[3];
    float ts2 = sm[4] + sm[5] + sm[6] + sm[7];
    float mu = ts / SS;
    float var = (ts2 - SS * mu * mu) / (SS - 1);
    smu = mu;
    srs = rsqrtf(var + 2.220446049250313e-16f);
  }
  __syncthreads();
  float mu = smu, rs = srs;
  float scale = sqrtf(stats[BB + b] + 2.220446049250313e-16f);
  float mean0 = stats[b];
  for (int j = tid; j < SS; j += 256) {
    out[(size_t)b * SS + j] = (rowbuf[j] - mu) * rs * scale + mean0;
  }
}

extern "C" void kernel_launch(void* const* d_in, const int* in_sizes, int n_in,
                              void* d_out, int out_size, void* d_ws, size_t ws_size,
                              hipStream_t stream) {
  const float* x         = (const float*)d_in[0];
  const float* attn_ln_g = (const float*)d_in[1];
  const float* attn_ln_b = (const float*)d_in[2];
  const float* ipw       = (const float*)d_in[3];
  const float* ipb       = (const float*)d_in[4];
  const float* out_w     = (const float*)d_in[5];
  const float* out_b     = (const float*)d_in[6];
  const float* mlp_ln_g  = (const float*)d_in[7];
  const float* mlp_ln_b  = (const float*)d_in[8];
  const float* W1        = (const float*)d_in[9];
  const float* b1        = (const float*)d_in[10];
  const float* W2        = (const float*)d_in[11];
  const float* b2        = (const float*)d_in[12];

  float* ws    = (float*)d_ws;
  float* xA    = ws;                              // 65536 f (attn-0 output)
  float* xB    = xA + BB * SS;                    // 65536 f (attn-1 output)
  __bf16* ubf  = (__bf16*)(xB + BB * SS);         // 65536 bf16 (32768 f)
  __bf16* hbf  = (__bf16*)(xB + BB * SS + 32768); // 196608 bf16 (98304 f)
  float* part  = xB + BB * SS + 32768 + 98304;    // 786432 f (3.1 MB), [ks][b][s]
  float* stats = part + (size_t)KS2 * 32 * SS;    // 64 f

  // ---- layer 0 ----
  k_attn<<<dim3(SS / 128, BB), 256, 0, stream>>>(x, xA,
                                                 attn_ln_g, attn_ln_b,
                                                 ipw, ipb, out_w, out_b,
                                                 stats, nullptr, nullptr);
  k_ln_bf<<<BB, 256, 0, stream>>>(xA, mlp_ln_g, mlp_ln_b, ubf);
  k_gemm1<<<EE / 32, 256, 0, stream>>>(ubf, W1, b1, hbf);
  k_gemm2<<<dim3(SS / 32, KS2), 256, 0, stream>>>(hbf, W2, part, EE);

  // ---- layer 1 (attn fuses layer-0 MLP tail) ----
  k_attn<<<dim3(SS / 128, BB), 256, 0, stream>>>(xA, xB,
                                                 attn_ln_g + SS, attn_ln_b + SS,
                                                 ipw + 3, ipb + 3, out_w + 1, out_b + 1,
                                                 nullptr, part, b2);
  k_ln_bf<<<BB, 256, 0, stream>>>(xB, mlp_ln_g + SS, mlp_ln_b + SS, ubf);
  k_gemm1<<<EE / 32, 256, 0, stream>>>(ubf, W1 + (size_t)EE * SS, b1 + EE, hbf);
  k_gemm2<<<dim3(SS / 32, KS2), 256, 0, stream>>>(hbf, W2 + (size_t)SS * EE, part, EE);

  // ---- final (fuses layer-1 MLP tail) ----
  k_final<<<BB, 256, 0, stream>>>(xB, part, b2 + SS, stats, (float*)d_out);
}

// Round 16
// 108.045 us; speedup vs baseline: 4.4841x; 1.0992x over previous
//
#include <hip/hip_runtime.h>
#include <math.h>

#define BB 32
#define SS 2048
#define EE 6144
#define KS2 12   // K-split gemm2 (K=6144, 512 k per block)

typedef __bf16 bf16x8 __attribute__((ext_vector_type(8)));
typedef float f32x16 __attribute__((ext_vector_type(16)));
typedef float f32x4 __attribute__((ext_vector_type(4)));
typedef float f32x2 __attribute__((ext_vector_type(2)));

// ---------------- fused [MLP-tail +] LN + attention + residual ----------------
// grid (SS/128, BB); block 512 = 8 waves (4 waves/SIMD for TLP).
// Input row = xin[b]                      (mlpPart == nullptr)
//           = xin[b] + b2 + sum_ks part   (mlpPart != nullptr, b-major part)
// xout = attn(LN(row)) + row.  If stats != nullptr, block x==0 emits
// mean/var(ddof=1) of the input row.
// Phase 3 uses f32x2-packed math (v_pk_fma_f32) for the 2 rows per thread.
__global__ __launch_bounds__(512) void k_attn(const float* __restrict__ xin,
                                              float* __restrict__ xout,
                                              const float* __restrict__ g,
                                              const float* __restrict__ be,
                                              const float* __restrict__ ipw,
                                              const float* __restrict__ ipb,
                                              const float* __restrict__ owp,
                                              const float* __restrict__ obp,
                                              float* __restrict__ stats,
                                              const float* __restrict__ mlpPart,
                                              const float* __restrict__ b2) {
  int b = blockIdx.y;
  const float* xrow = xin + b * SS;
  __shared__ float rowbuf[SS];        // 8 KB reconstructed input row
  __shared__ float2 uv[SS];           // (u_j, v_j)  16 KB
  __shared__ float red[16], red2[16];
  __shared__ float smu, srs, sk1, sk2;
  __shared__ float sp[2][7][2][64];   // 7 KB partials from waves 1..7
  int tid = threadIdx.x;
  int lane = tid & 63, wid = tid >> 6;

  // phase 0: build input row (512 threads -> one float4 each)
  {
    float4* rb4 = reinterpret_cast<float4*>(rowbuf);
    const float4* xr4 = reinterpret_cast<const float4*>(xrow);
    if (mlpPart) {
      const float4* b24 = reinterpret_cast<const float4*>(b2);
      float4 xv = xr4[tid];
      float4 bv = b24[tid];
      float4 pv[KS2];
#pragma unroll
      for (int ks = 0; ks < KS2; ks++)
        pv[ks] = reinterpret_cast<const float4*>(mlpPart + (size_t)ks * (32 * SS) + (size_t)b * SS)[tid];
      float4 o;
      o.x = xv.x + bv.x; o.y = xv.y + bv.y; o.z = xv.z + bv.z; o.w = xv.w + bv.w;
#pragma unroll
      for (int ks = 0; ks < KS2; ks++) {
        o.x += pv[ks].x; o.y += pv[ks].y; o.z += pv[ks].z; o.w += pv[ks].w;
      }
      rb4[tid] = o;
    } else {
      rb4[tid] = xr4[tid];
    }
  }
  __syncthreads();

  // phase 1: LN row stats
  float s = 0.f, s2 = 0.f;
  for (int j = tid; j < SS; j += 512) { float v = rowbuf[j]; s += v; s2 += v * v; }
  for (int off = 32; off; off >>= 1) { s += __shfl_down(s, off); s2 += __shfl_down(s2, off); }
  if (lane == 0) { red[wid] = s; red[8 + wid] = s2; }
  __syncthreads();
  if (tid == 0) {
    float ts = 0.f, ts2 = 0.f;
#pragma unroll
    for (int w = 0; w < 8; w++) { ts += red[w]; ts2 += red[8 + w]; }
    float mu = ts / SS;
    float var = ts2 / SS - mu * mu;
    smu = mu; srs = rsqrtf(var + 1e-5f);
    if (stats && blockIdx.x == 0) {
      stats[b] = mu;
      stats[BB + b] = (ts2 - SS * mu * mu) / (SS - 1);
    }
  }
  __syncthreads();
  float mu = smu, rs = srs;
  float wq = ipw[0], wk = ipw[1], wv = ipw[2];
  float bq = ipb[0], bk = ipb[1], bv = ipb[2];

  // phase 2: stage (u, v) into LDS + track u extremes (k is affine in u)
  float umax = -1e30f, umin = 1e30f;
  for (int j = tid; j < SS; j += 512) {
    float u = (rowbuf[j] - mu) * rs * g[j] + be[j];
    uv[j] = make_float2(u, fmaf(u, wv, bv));
    umax = fmaxf(umax, u);
    umin = fminf(umin, u);
  }
  for (int off = 32; off; off >>= 1) {
    umax = fmaxf(umax, __shfl_down(umax, off));
    umin = fminf(umin, __shfl_down(umin, off));
  }
  if (lane == 0) { red2[wid] = umax; red2[8 + wid] = umin; }
  __syncthreads();
  if (tid == 0) {
    float ux = -1e30f, un = 1e30f;
#pragma unroll
    for (int w = 0; w < 8; w++) { ux = fmaxf(ux, red2[w]); un = fminf(un, red2[8 + w]); }
    sk1 = fmaf(ux, wk, bk);
    sk2 = fmaf(un, wk, bk);
  }
  __syncthreads();
  float k1 = sk1, k2 = sk2;

  // phase 3: packed softmax-weighted sum; arg = L2E*(q*wk)*u_j + L2E*(q*bk - m)
  const float L2E = 1.4426950408889634f;
  int i0 = blockIdx.x << 7;
  float q0 = fmaf(uv[i0 + lane].x, wq, bq);
  float q1 = fmaf(uv[i0 + 64 + lane].x, wq, bq);
  float m0 = fmaxf(q0 * k1, q0 * k2);
  float m1 = fmaxf(q1 * k1, q1 * k2);
  f32x2 a01 = {L2E * q0 * wk, L2E * q1 * wk};
  f32x2 c01 = {L2E * (q0 * bk - m0), L2E * (q1 * bk - m1)};
  f32x2 s01 = {0.f, 0.f}, t01 = {0.f, 0.f};
  int j0 = wid << 8;
#pragma unroll 4
  for (int j = j0; j < j0 + 256; j++) {
    float2 c = uv[j];
    f32x2 arg = a01 * c.x + c01;                       // v_pk_fma_f32
    f32x2 e = {__builtin_amdgcn_exp2f(arg[0]),
               __builtin_amdgcn_exp2f(arg[1])};        // 2x v_exp_f32
    s01 += e;                                          // v_pk_add_f32
    t01 += e * c.y;                                    // v_pk_fma_f32
  }
  if (wid) {
    sp[0][wid - 1][0][lane] = s01[0]; sp[0][wid - 1][1][lane] = s01[1];
    sp[1][wid - 1][0][lane] = t01[0]; sp[1][wid - 1][1][lane] = t01[1];
  }
  __syncthreads();
  if (wid == 0) {
    float s0 = s01[0], t0 = t01[0], s1 = s01[1], t1 = t01[1];
#pragma unroll
    for (int w = 0; w < 7; w++) {
      s0 += sp[0][w][0][lane];
      t0 += sp[1][w][0][lane];
      s1 += sp[0][w][1][lane];
      t1 += sp[1][w][1][lane];
    }
    float ow = owp[0], ob = obp[0];
    int i = i0 + lane;
    xout[b * SS + i] = fmaf(t0 / s0, ow, ob) + rowbuf[i];
    xout[b * SS + i + 64] = fmaf(t1 / s1, ow, ob) + rowbuf[i + 64];
  }
}

// ---------------- LayerNorm -> bf16 B-fragment layout Ubf[k/8][32][8] ----------------
__global__ __launch_bounds__(256) void k_ln_bf(const float* __restrict__ x,
                                               const float* __restrict__ g,
                                               const float* __restrict__ be,
                                               __bf16* __restrict__ ubf) {
  int b = blockIdx.x;
  const float* row = x + b * SS;
  float s = 0.f, s2 = 0.f;
  for (int j = threadIdx.x; j < SS; j += 256) { float v = row[j]; s += v; s2 += v * v; }
  __shared__ float sm[8];
  __shared__ float smu, srs;
  for (int off = 32; off; off >>= 1) { s += __shfl_down(s, off); s2 += __shfl_down(s2, off); }
  int lane = threadIdx.x & 63, wid = threadIdx.x >> 6;
  if (lane == 0) { sm[wid] = s; sm[4 + wid] = s2; }
  __syncthreads();
  if (threadIdx.x == 0) {
    float ts = sm[0] + sm[1] + sm[2] + sm[3];
    float ts2 = sm[4] + sm[5] + sm[6] + sm[7];
    float mu = ts / SS;
    float var = ts2 / SS - mu * mu;
    smu = mu;
    srs = rsqrtf(var + 1e-5f);
  }
  __syncthreads();
  float mu = smu, rs = srs;
  int t = threadIdx.x;
  float4 v0 = *reinterpret_cast<const float4*>(row + t * 8);
  float4 v1 = *reinterpret_cast<const float4*>(row + t * 8 + 4);
  float4 g0 = *reinterpret_cast<const float4*>(g + t * 8);
  float4 g1 = *reinterpret_cast<const float4*>(g + t * 8 + 4);
  float4 b0 = *reinterpret_cast<const float4*>(be + t * 8);
  float4 b1 = *reinterpret_cast<const float4*>(be + t * 8 + 4);
  bf16x8 o;
  o[0] = (__bf16)((v0.x - mu) * rs * g0.x + b0.x);
  o[1] = (__bf16)((v0.y - mu) * rs * g0.y + b0.y);
  o[2] = (__bf16)((v0.z - mu) * rs * g0.z + b0.z);
  o[3] = (__bf16)((v0.w - mu) * rs * g0.w + b0.w);
  o[4] = (__bf16)((v1.x - mu) * rs * g1.x + b1.x);
  o[5] = (__bf16)((v1.y - mu) * rs * g1.y + b1.y);
  o[6] = (__bf16)((v1.z - mu) * rs * g1.z + b1.z);
  o[7] = (__bf16)((v1.w - mu) * rs * g1.w + b1.w);
  *reinterpret_cast<bf16x8*>(ubf + t * 256 + b * 8) = o;
}

// ---------------- gemm1 full-K: h = LeakyReLU(W1 u + b1) -> hbf directly ----------------
__global__ __launch_bounds__(256, 2) void k_gemm1(const __bf16* __restrict__ Ubf,
                                                  const float* __restrict__ W,
                                                  const float* __restrict__ bias,
                                                  __bf16* __restrict__ hbf) {
  __shared__ float ls[3][16][64];  // 12 KB cross-wave reduce
  __shared__ float st[32][33];     // 4.2 KB epilogue staging
  int tid = threadIdx.x;
  int w = tid >> 6, lane = tid & 63;
  int l31 = lane & 31, h = lane >> 5;
  int e0 = blockIdx.x << 5;

  f32x16 acc = {0.f, 0.f, 0.f, 0.f, 0.f, 0.f, 0.f, 0.f,
                0.f, 0.f, 0.f, 0.f, 0.f, 0.f, 0.f, 0.f};
#pragma unroll
  for (int c = 0; c < 4; ++c) {
    int kc = (w << 9) + (c << 7);
    const float* wp = W + (size_t)(e0 + l31) * SS + kc + (h << 3);
    const __bf16* up = Ubf + (size_t)((kc >> 3) + h) * 256 + (l31 << 3);
    f32x4 wb[16];
    bf16x8 ub[8];
#pragma unroll
    for (int t = 0; t < 8; ++t) {
      wb[2 * t]     = *reinterpret_cast<const f32x4*>(wp + (t << 4));
      wb[2 * t + 1] = *reinterpret_cast<const f32x4*>(wp + (t << 4) + 4);
      ub[t]         = *reinterpret_cast<const bf16x8*>(up + (t << 9));
    }
#pragma unroll
    for (int t = 0; t < 8; ++t) {
      bf16x8 av;
      av[0] = (__bf16)wb[2 * t][0];     av[1] = (__bf16)wb[2 * t][1];
      av[2] = (__bf16)wb[2 * t][2];     av[3] = (__bf16)wb[2 * t][3];
      av[4] = (__bf16)wb[2 * t + 1][0]; av[5] = (__bf16)wb[2 * t + 1][1];
      av[6] = (__bf16)wb[2 * t + 1][2]; av[7] = (__bf16)wb[2 * t + 1][3];
      acc = __builtin_amdgcn_mfma_f32_32x32x16_bf16(av, ub[t], acc, 0, 0, 0);
    }
  }

  if (w) {
#pragma unroll
    for (int r = 0; r < 16; ++r) ls[w - 1][r][lane] = acc[r];
  }
  __syncthreads();
  if (w == 0) {
#pragma unroll
    for (int r = 0; r < 16; ++r) {
      float v = acc[r] + ls[0][r][lane] + ls[1][r][lane] + ls[2][r][lane];
      int row = (r & 3) + ((r >> 2) << 3) + (h << 2);
      st[row][l31] = v;
    }
  }
  __syncthreads();
  if (tid < 128) {
    int eg = tid >> 5, b = tid & 31;
    bf16x8 o;
#pragma unroll
    for (int j = 0; j < 8; j++) {
      float v = st[eg * 8 + j][b] + bias[e0 + eg * 8 + j];
      o[j] = (__bf16)(v >= 0.f ? v : 0.5f * v);
    }
    *reinterpret_cast<bf16x8*>(hbf + (size_t)((e0 >> 3) + eg) * 256 + b * 8) = o;
  }
}

// ---------------- gemm2 split-K, b-major partial store part[ks][b][s] ----------------
__global__ __launch_bounds__(256, 2) void k_gemm2(const __bf16* __restrict__ Ubf,
                                                  const float* __restrict__ W,
                                                  float* __restrict__ part,
                                                  int K) {
  __shared__ float ls[3][16][64];  // 12 KB
  __shared__ float st[32][33];     // 4.2 KB transpose staging
  int tid = threadIdx.x;
  int w = tid >> 6, lane = tid & 63;
  int l31 = lane & 31, h = lane >> 5;
  int s0 = blockIdx.x << 5;
  int kc = (blockIdx.y << 9) + (w << 7);
  const float* wp = W + (size_t)(s0 + l31) * K + kc + (h << 3);
  const __bf16* up = Ubf + (size_t)((kc >> 3) + h) * 256 + (l31 << 3);

  f32x4 wb[16];
  bf16x8 ub[8];
#pragma unroll
  for (int t = 0; t < 8; ++t) {
    wb[2 * t]     = *reinterpret_cast<const f32x4*>(wp + (t << 4));
    wb[2 * t + 1] = *reinterpret_cast<const f32x4*>(wp + (t << 4) + 4);
    ub[t]         = *reinterpret_cast<const bf16x8*>(up + (t << 9));
  }

  f32x16 acc = {0.f, 0.f, 0.f, 0.f, 0.f, 0.f, 0.f, 0.f,
                0.f, 0.f, 0.f, 0.f, 0.f, 0.f, 0.f, 0.f};
#pragma unroll
  for (int t = 0; t < 8; ++t) {
    bf16x8 av;
    av[0] = (__bf16)wb[2 * t][0];     av[1] = (__bf16)wb[2 * t][1];
    av[2] = (__bf16)wb[2 * t][2];     av[3] = (__bf16)wb[2 * t][3];
    av[4] = (__bf16)wb[2 * t + 1][0]; av[5] = (__bf16)wb[2 * t + 1][1];
    av[6] = (__bf16)wb[2 * t + 1][2]; av[7] = (__bf16)wb[2 * t + 1][3];
    acc = __builtin_amdgcn_mfma_f32_32x32x16_bf16(av, ub[t], acc, 0, 0, 0);
  }

  if (w) {
#pragma unroll
    for (int r = 0; r < 16; ++r) ls[w - 1][r][lane] = acc[r];
  }
  __syncthreads();
  if (w == 0) {
#pragma unroll
    for (int r = 0; r < 16; ++r) {
      float v = acc[r] + ls[0][r][lane] + ls[1][r][lane] + ls[2][r][lane];
      int row = (r & 3) + ((r >> 2) << 3) + (h << 2);   // s_local
      st[row][l31] = v;                                  // [s_local][b]
    }
  }
  __syncthreads();
  // b-major store: thread t -> b = t>>3, s-quad i0 = (t&7)*4
  {
    float* out = part + (size_t)blockIdx.y * (32 * SS);
    int bb = tid >> 3, i0 = (tid & 7) << 2;
    float4 o4;
    o4.x = st[i0 + 0][bb];
    o4.y = st[i0 + 1][bb];
    o4.z = st[i0 + 2][bb];
    o4.w = st[i0 + 3][bb];
    *reinterpret_cast<float4*>(out + (size_t)bb * SS + s0 + i0) = o4;
  }
}

// ---------------- final: row = xA + b2 + sum part; renorm to original stats ----------------
__global__ __launch_bounds__(256) void k_final(const float* __restrict__ xbuf,
                                               const float* __restrict__ part,
                                               const float* __restrict__ b2,
                                               const float* __restrict__ stats,
                                               float* __restrict__ out) {
  int b = blockIdx.x;
  __shared__ float rowbuf[SS];
  __shared__ float sm[8];
  __shared__ float smu, srs;
  int tid = threadIdx.x;
  float4* rb4 = reinterpret_cast<float4*>(rowbuf);
  const float4* xr4 = reinterpret_cast<const float4*>(xbuf + (size_t)b * SS);
  const float4* b24 = reinterpret_cast<const float4*>(b2);
#pragma unroll
  for (int it = 0; it < 2; ++it) {
    int jj = tid + (it << 8);
    float4 xv = xr4[jj];
    float4 bv = b24[jj];
    float4 pv[KS2];
#pragma unroll
    for (int ks = 0; ks < KS2; ks++)
      pv[ks] = reinterpret_cast<const float4*>(part + (size_t)ks * (32 * SS) + (size_t)b * SS)[jj];
    float4 o;
    o.x = xv.x + bv.x; o.y = xv.y + bv.y; o.z = xv.z + bv.z; o.w = xv.w + bv.w;
#pragma unroll
    for (int ks = 0; ks < KS2; ks++) {
      o.x += pv[ks].x; o.y += pv[ks].y; o.z += pv[ks].z; o.w += pv[ks].w;
    }
    rb4[jj] = o;
  }
  __syncthreads();

  float s = 0.f, s2 = 0.f;
  for (int j = tid; j < SS; j += 256) { float v = rowbuf[j]; s += v; s2 += v * v; }
  for (int off = 32; off; off >>= 1) { s += __shfl_down(s, off); s2 += __shfl_down(s2, off); }
  int lane = tid & 63, wid = tid >> 6;
  if (lane == 0) { sm[wid] = s; sm[4 + wid] = s2; }
  __syncthreads();
  if (tid == 0) {
    float ts = sm[0] + sm[1] + sm[2] + sm[3];
    float ts2 = sm[4] + sm[5] + sm[6] + sm[7];
    float mu = ts / SS;
    float var = (ts2 - SS * mu * mu) / (SS - 1);
    smu = mu;
    srs = rsqrtf(var + 2.220446049250313e-16f);
  }
  __syncthreads();
  float mu = smu, rs = srs;
  float scale = sqrtf(stats[BB + b] + 2.220446049250313e-16f);
  float mean0 = stats[b];
  for (int j = tid; j < SS; j += 256) {
    out[(size_t)b * SS + j] = (rowbuf[j] - mu) * rs * scale + mean0;
  }
}

extern "C" void kernel_launch(void* const* d_in, const int* in_sizes, int n_in,
                              void* d_out, int out_size, void* d_ws, size_t ws_size,
                              hipStream_t stream) {
  const float* x         = (const float*)d_in[0];
  const float* attn_ln_g = (const float*)d_in[1];
  const float* attn_ln_b = (const float*)d_in[2];
  const float* ipw       = (const float*)d_in[3];
  const float* ipb       = (const float*)d_in[4];
  const float* out_w     = (const float*)d_in[5];
  const float* out_b     = (const float*)d_in[6];
  const float* mlp_ln_g  = (const float*)d_in[7];
  const float* mlp_ln_b  = (const float*)d_in[8];
  const float* W1        = (const float*)d_in[9];
  const float* b1        = (const float*)d_in[10];
  const float* W2        = (const float*)d_in[11];
  const float* b2        = (const float*)d_in[12];

  float* ws    = (float*)d_ws;
  float* xA    = ws;                              // 65536 f (attn-0 output)
  float* xB    = xA + BB * SS;                    // 65536 f (attn-1 output)
  __bf16* ubf  = (__bf16*)(xB + BB * SS);         // 65536 bf16 (32768 f)
  __bf16* hbf  = (__bf16*)(xB + BB * SS + 32768); // 196608 bf16 (98304 f)
  float* part  = xB + BB * SS + 32768 + 98304;    // 786432 f (3.1 MB), [ks][b][s]
  float* stats = part + (size_t)KS2 * 32 * SS;    // 64 f

  // ---- layer 0 ----
  k_attn<<<dim3(SS / 128, BB), 512, 0, stream>>>(x, xA,
                                                 attn_ln_g, attn_ln_b,
                                                 ipw, ipb, out_w, out_b,
                                                 stats, nullptr, nullptr);
  k_ln_bf<<<BB, 256, 0, stream>>>(xA, mlp_ln_g, mlp_ln_b, ubf);
  k_gemm1<<<EE / 32, 256, 0, stream>>>(ubf, W1, b1, hbf);
  k_gemm2<<<dim3(SS / 32, KS2), 256, 0, stream>>>(hbf, W2, part, EE);

  // ---- layer 1 (attn fuses layer-0 MLP tail) ----
  k_attn<<<dim3(SS / 128, BB), 512, 0, stream>>>(xA, xB,
                                                 attn_ln_g + SS, attn_ln_b + SS,
                                                 ipw + 3, ipb + 3, out_w + 1, out_b + 1,
                                                 nullptr, part, b2);
  k_ln_bf<<<BB, 256, 0, stream>>>(xB, mlp_ln_g + SS, mlp_ln_b + SS, ubf);
  k_gemm1<<<EE / 32, 256, 0, stream>>>(ubf, W1 + (size_t)EE * SS, b1 + EE, hbf);
  k_gemm2<<<dim3(SS / 32, KS2), 256, 0, stream>>>(hbf, W2 + (size_t)SS * EE, part, EE);

  // ---- final (fuses layer-1 MLP tail) ----
  k_final<<<BB, 256, 0, stream>>>(xB, part, b2 + SS, stats, (float*)d_out);
}